// Round 2
// baseline (3934.790 us; speedup 1.0000x reference)
//
#include <hip/hip_runtime.h>
#include <hip/hip_bf16.h>
#include <math.h>

#define B_ 2
#define S_ 2048
#define E_ 2048
#define H_ 16
#define NOPE_ 64
#define ROPE_ 32
#define V_ 64
#define KVR_ 256
#define QKD_ 96
#define SCALE_ 0.10206207261596577f  /* 96^-0.5 */

// ---------------- Generic tiled GEMM: C = A @ B^T ----------------
// A: (M,K) row-major, B: (N,K) row-major. BM=BN=64, BK=16, 256 threads.
__global__ __launch_bounds__(256) void gemm_tn(const float* __restrict__ A,
                                               const float* __restrict__ Bm,
                                               float* __restrict__ C,
                                               int M, int N, int K) {
    __shared__ float As[16][68];
    __shared__ float Bs[16][68];
    int tid = threadIdx.x;
    int tx = tid & 15, ty = tid >> 4;
    int m0 = blockIdx.y * 64, n0 = blockIdx.x * 64;
    float acc[4][4] = {};
    for (int k0 = 0; k0 < K; k0 += 16) {
#pragma unroll
        for (int it = 0; it < 4; ++it) {
            int idx = tid + it * 256;
            int r = idx >> 4, c = idx & 15;
            int m = m0 + r;
            As[c][r] = (m < M) ? A[(size_t)m * K + (k0 + c)] : 0.f;
            int n = n0 + r;
            Bs[c][r] = (n < N) ? Bm[(size_t)n * K + (k0 + c)] : 0.f;
        }
        __syncthreads();
#pragma unroll
        for (int kk = 0; kk < 16; ++kk) {
            float4 a = *(const float4*)&As[kk][ty * 4];
            float4 b = *(const float4*)&Bs[kk][tx * 4];
            acc[0][0] += a.x * b.x; acc[0][1] += a.x * b.y; acc[0][2] += a.x * b.z; acc[0][3] += a.x * b.w;
            acc[1][0] += a.y * b.x; acc[1][1] += a.y * b.y; acc[1][2] += a.y * b.z; acc[1][3] += a.y * b.w;
            acc[2][0] += a.z * b.x; acc[2][1] += a.z * b.y; acc[2][2] += a.z * b.z; acc[2][3] += a.z * b.w;
            acc[3][0] += a.w * b.x; acc[3][1] += a.w * b.y; acc[3][2] += a.w * b.z; acc[3][3] += a.w * b.w;
        }
        __syncthreads();
    }
#pragma unroll
    for (int i = 0; i < 4; ++i) {
        int m = m0 + ty * 4 + i;
        if (m >= M) continue;
#pragma unroll
        for (int j = 0; j < 4; ++j) {
            int n = n0 + tx * 4 + j;
            if (n < N) C[(size_t)m * N + n] = acc[i][j];
        }
    }
}

// ---------------- RoPE on q_pe (in place on fp32 q buffer) ----------------
__global__ __launch_bounds__(256) void rope_q_kernel(float* __restrict__ q) {
    int idx = blockIdx.x * 256 + threadIdx.x;  // pair index over B*S*H*16
    if (idx >= B_ * S_ * H_ * (ROPE_ / 2)) return;
    int j = idx & 15;
    int s = (idx >> 8) & (S_ - 1);
    double freq = exp(-(double)(2 * j) * (9.210340371976184 / 32.0));  // 10000^{-2j/32}
    double ang = (double)s * freq;
    float c = (float)cos(ang), sn = (float)sin(ang);
    size_t base = (size_t)(idx >> 4) * QKD_ + NOPE_ + 2 * j;
    float x0 = q[base], x1 = q[base + 1];
    q[base]     = x0 * c - x1 * sn;
    q[base + 1] = x0 * sn + x1 * c;
}

// ---------------- LayerNorm(kv_c) + RoPE(k_pe) ----------------
__global__ __launch_bounds__(256) void ln_rope_kernel(const float* __restrict__ kvraw,
                                                      const float* __restrict__ g,
                                                      const float* __restrict__ bta,
                                                      float* __restrict__ kv_c,
                                                      float* __restrict__ kpe) {
    int r = blockIdx.x;  // 0..B*S-1
    int tid = threadIdx.x;
    int lane = tid & 63, w = tid >> 6;
    float x = kvraw[(size_t)r * 288 + tid];
    float v1 = x, v2 = x * x;
#pragma unroll
    for (int o = 32; o; o >>= 1) { v1 += __shfl_down(v1, o); v2 += __shfl_down(v2, o); }
    __shared__ float s1[4], s2[4], stats[2];
    if (lane == 0) { s1[w] = v1; s2[w] = v2; }
    __syncthreads();
    if (tid == 0) {
        float S1 = s1[0] + s1[1] + s1[2] + s1[3];
        float S2 = s2[0] + s2[1] + s2[2] + s2[3];
        float mean = S1 / 256.0f;
        float var = S2 / 256.0f - mean * mean;
        stats[0] = mean;
        stats[1] = rsqrtf(var + 1e-5f);
    }
    __syncthreads();
    float y = (x - stats[0]) * stats[1] * g[tid] + bta[tid];
    kv_c[(size_t)r * 256 + tid] = y;
    if (tid < 16) {
        int j = tid;
        int s = r & (S_ - 1);
        double freq = exp(-(double)(2 * j) * (9.210340371976184 / 32.0));
        double ang = (double)s * freq;
        float c = (float)cos(ang), sn = (float)sin(ang);
        float x0 = kvraw[(size_t)r * 288 + 256 + 2 * j];
        float x1 = kvraw[(size_t)r * 288 + 256 + 2 * j + 1];
        kpe[(size_t)r * 32 + 2 * j]     = x0 * c - x1 * sn;
        kpe[(size_t)r * 32 + 2 * j + 1] = x0 * sn + x1 * c;
    }
}

// ---------------- C2 / P2 rows (pos-enc projected through fc_c / fc_p) ----------------
__global__ __launch_bounds__(64) void c2p2_kernel(const float* __restrict__ fcw_c,
                                                  const float* __restrict__ fcb_c,
                                                  const float* __restrict__ fcw_p,
                                                  const float* __restrict__ fcb_p,
                                                  float* __restrict__ C2,
                                                  float* __restrict__ P2) {
    int t = blockIdx.x;
    int k = threadIdx.x;  // 0..63
    __shared__ float Crow[256], Prow[256];
    for (int i = k; i < 128; i += 64) {
        double div = exp(-(double)i * (9.210340371976184 / 128.0));  // 10000^{-i/128}
        double ap = (double)t * div;
        Prow[2 * i]     = (float)sin(ap);
        Prow[2 * i + 1] = (float)cos(ap);
        double ac = (double)(t >> 1) * div;
        Crow[2 * i]     = (float)sin(ac);
        Crow[2 * i + 1] = (float)cos(ac);
    }
    __syncthreads();
    float sc = fcb_c[k], sp = fcb_p[k];
    for (int c = 0; c < 256; ++c) {
        sc += Crow[c] * fcw_c[(size_t)k * 256 + c];
        sp += Prow[c] * fcw_p[(size_t)k * 256 + c];
    }
    C2[(size_t)t * 64 + k] = sc;
    P2[(size_t)t * 64 + k] = sp;
}

// ---------------- gate values (only diagonal 2x2 blocks of Wg survive the chunk mask) --
__global__ __launch_bounds__(256) void gates_kernel(const float* __restrict__ C2,
                                                    const float* __restrict__ P2,
                                                    float* __restrict__ g0,
                                                    float* __restrict__ g1) {
    int t = blockIdx.x * 256 + threadIdx.x;
    if (t >= S_) return;
    float d0 = 0.f;
    for (int k = 0; k < 64; ++k) d0 += C2[(size_t)t * 64 + k] * P2[(size_t)t * 64 + k];
    g0[t] = 1.0f / (1.0f + expf(-d0));
    float gg = 0.f;
    if (t & 1) {
        float d1 = 0.f;
        for (int k = 0; k < 64; ++k) d1 += C2[(size_t)t * 64 + k] * P2[(size_t)(t - 1) * 64 + k];
        gg = 1.0f / (1.0f + expf(-d1));
    }
    g1[t] = gg;
}

// ---------------- kv_t / k_pe_t (gated 2-term combination) ----------------
__global__ __launch_bounds__(256) void kvt_kernel(const float* __restrict__ kv_c,
                                                  const float* __restrict__ kpe,
                                                  const float* __restrict__ g0,
                                                  const float* __restrict__ g1,
                                                  float* __restrict__ kvt,
                                                  float* __restrict__ kpet) {
    int r = blockIdx.x;  // 0..B*S-1
    int tid = threadIdx.x;
    int t = r & (S_ - 1);
    float a = g0[t], bb = g1[t];
    float v = a * kv_c[(size_t)r * 256 + tid];
    if (t & 1) v += bb * kv_c[(size_t)(r - 1) * 256 + tid];
    kvt[(size_t)r * 256 + tid] = v;
    if (tid < 32) {
        float u = a * kpe[(size_t)r * 32 + tid];
        if (t & 1) u += bb * kpe[(size_t)(r - 1) * 32 + tid];
        kpet[(size_t)r * 32 + tid] = u;
    }
}

// ---------------- attention: one block per (b,s,h); fused q_abs, online softmax over
//                  visible keys, fused output V-projection ----------------
__global__ __launch_bounds__(256) void attn_kernel(const float* __restrict__ q,
                                                   const float* __restrict__ kvt,
                                                   const float* __restrict__ kpet,
                                                   const float* __restrict__ wkv_b,
                                                   float* __restrict__ out_pre) {
    int h = blockIdx.x, s = blockIdx.y, b = blockIdx.z;
    int tid = threadIdx.x;
    int lane = tid & 63, w = tid >> 6;
    size_t qi = ((size_t)(b * S_ + s) * H_ + h);

    __shared__ float qn[64];
    __shared__ float qa[256];
    if (tid < 64) qn[tid] = q[qi * QKD_ + tid];
    __syncthreads();
    // q_abs[c] = sum_d q_nope[d] * wkv_b[h,(d),c]
    {
        const float* wn = wkv_b + (size_t)h * 128 * 256 + tid;
        float acc = 0.f;
#pragma unroll 8
        for (int d = 0; d < 64; ++d) acc += qn[d] * wn[(size_t)d * 256];
        qa[tid] = acc;
    }
    __syncthreads();

    float qv0 = qa[lane];
    float qv1 = qa[64 + lane];
    float qv2 = qa[128 + lane];
    float qv3 = qa[192 + lane];
    float qp = (lane < 32) ? q[qi * QKD_ + NOPE_ + lane] : 0.f;
    const float* kvb = kvt + (size_t)b * S_ * 256;
    const float* kpb = kpet + (size_t)b * S_ * 32;

    float m = -INFINITY, l = 0.f;
    float a0 = 0.f, a1 = 0.f, a2 = 0.f, a3 = 0.f;

    auto do_key = [&](int t) {
        const float* kr = kvb + (size_t)t * 256;
        float k0 = kr[lane], k1 = kr[64 + lane], k2 = kr[128 + lane], k3 = kr[192 + lane];
        float kp = (lane < 32) ? kpb[(size_t)t * 32 + lane] : 0.f;
        float d = qv0 * k0 + qv1 * k1 + qv2 * k2 + qv3 * k3 + qp * kp;
#pragma unroll
        for (int o = 32; o; o >>= 1) d += __shfl_xor(d, o);
        float sc = d * SCALE_;
        float mn = fmaxf(m, sc);
        float al = __expf(m - mn);  // exp(-inf)=0 on first key
        float p = __expf(sc - mn);
        l = l * al + p;
        a0 = a0 * al + p * k0;
        a1 = a1 * al + p * k1;
        a2 = a2 * al + p * k2;
        a3 = a3 * al + p * k3;
        m = mn;
    };

    int umax = (s >= 1) ? ((s - 1) >> 1) : -1;  // odd keys t=2u+1, u<=umax
    for (int u = w; u <= umax; u += 4) do_key(2 * u + 1);
    if (((s & 1) == 0) && w == 0) do_key(s);  // self key for even s

    __shared__ float sacc[4][256];
    __shared__ float sm[4], sl[4];
    __shared__ float xbuf[256];
    __shared__ float pbuf[256];
    sacc[w][lane] = a0;
    sacc[w][64 + lane] = a1;
    sacc[w][128 + lane] = a2;
    sacc[w][192 + lane] = a3;
    if (lane == 0) { sm[w] = m; sl[w] = l; }
    __syncthreads();
    float m0 = fmaxf(fmaxf(sm[0], sm[1]), fmaxf(sm[2], sm[3]));
    float e0 = __expf(sm[0] - m0), e1 = __expf(sm[1] - m0);
    float e2 = __expf(sm[2] - m0), e3 = __expf(sm[3] - m0);
    float lt = e0 * sl[0] + e1 * sl[1] + e2 * sl[2] + e3 * sl[3];
    float xv = (e0 * sacc[0][tid] + e1 * sacc[1][tid] + e2 * sacc[2][tid] + e3 * sacc[3][tid]) / lt;
    xbuf[tid] = xv;
    __syncthreads();
    // fused out-projection: out_pre[b,s,h*64+d] = sum_c xbuf[c] * wkv_b[h*128+64+d, c]
    int d = tid >> 2, pp = tid & 3;
    const float* wv = wkv_b + ((size_t)(h * 128 + 64 + d)) * 256 + pp * 64;
    float sum = 0.f;
#pragma unroll 8
    for (int i = 0; i < 64; ++i) sum += xbuf[pp * 64 + i] * wv[i];
    pbuf[tid] = sum;
    __syncthreads();
    if (tid < 64) {
        float o = pbuf[tid * 4] + pbuf[tid * 4 + 1] + pbuf[tid * 4 + 2] + pbuf[tid * 4 + 3];
        out_pre[(size_t)(b * S_ + s) * (H_ * V_) + h * 64 + tid] = o;
    }
}

extern "C" void kernel_launch(void* const* d_in, const int* in_sizes, int n_in,
                              void* d_out, int out_size, void* d_ws, size_t ws_size,
                              hipStream_t stream) {
    const float* hs     = (const float*)d_in[0];
    const float* wq     = (const float*)d_in[1];
    const float* wkv_a  = (const float*)d_in[2];
    const float* ln_g   = (const float*)d_in[3];
    const float* ln_b   = (const float*)d_in[4];
    const float* wkv_b  = (const float*)d_in[5];
    const float* wo     = (const float*)d_in[6];
    const float* fc_c_w = (const float*)d_in[7];
    const float* fc_c_b = (const float*)d_in[8];
    const float* fc_p_w = (const float*)d_in[9];
    const float* fc_p_b = (const float*)d_in[10];
    float* out = (float*)d_out;

    const int M = B_ * S_;  // 4096
    float* ws = (float*)d_ws;
    size_t off = 0;
    float* q     = ws + off; off += (size_t)M * (H_ * QKD_);   // 4096x1536
    float* kvraw = ws + off; off += (size_t)M * 288;
    float* kv_c  = ws + off; off += (size_t)M * 256;
    float* kpe   = ws + off; off += (size_t)M * 32;
    float* C2    = ws + off; off += (size_t)S_ * 64;
    float* P2    = ws + off; off += (size_t)S_ * 64;
    float* g0    = ws + off; off += S_;
    float* g1    = ws + off; off += S_;
    float* kvt   = ws + off; off += (size_t)M * 256;
    float* kpet  = ws + off; off += (size_t)M * 32;
    float* outp  = ws + off; off += (size_t)M * (H_ * V_);
    (void)ws_size; (void)in_sizes; (void)n_in; (void)out_size;

    // 1) q = hs @ wq.T  (4096x2048 @ 2048x1536)
    gemm_tn<<<dim3(1536 / 64, M / 64), 256, 0, stream>>>(hs, wq, q, M, H_ * QKD_, E_);
    // 2) kv = hs @ wkv_a.T (4096x2048 @ 2048x288)
    gemm_tn<<<dim3(5, M / 64), 256, 0, stream>>>(hs, wkv_a, kvraw, M, KVR_ + ROPE_, E_);
    // 3) RoPE on q_pe
    rope_q_kernel<<<(B_ * S_ * H_ * 16 + 255) / 256, 256, 0, stream>>>(q);
    // 4) LayerNorm kv_c + RoPE k_pe
    ln_rope_kernel<<<M, 256, 0, stream>>>(kvraw, ln_g, ln_b, kv_c, kpe);
    // 5) gate pieces
    c2p2_kernel<<<S_, 64, 0, stream>>>(fc_c_w, fc_c_b, fc_p_w, fc_p_b, C2, P2);
    gates_kernel<<<(S_ + 255) / 256, 256, 0, stream>>>(C2, P2, g0, g1);
    // 6) kv_t / k_pe_t
    kvt_kernel<<<M, 256, 0, stream>>>(kv_c, kpe, g0, g1, kvt, kpet);
    // 7) attention (fused q_abs + softmax + V-projection)
    attn_kernel<<<dim3(H_, S_, B_), 256, 0, stream>>>(q, kvt, kpet, wkv_b, outp);
    // 8) final: out = outp @ wo.T (4096x1024 @ 1024x2048)
    gemm_tn<<<dim3(E_ / 64, M / 64), 256, 0, stream>>>(outp, wo, out, M, E_, H_ * V_);
}

// Round 3
// 1166.494 us; speedup vs baseline: 3.3732x; 3.3732x over previous
//
#include <hip/hip_runtime.h>
#include <hip/hip_bf16.h>
#include <math.h>

#define B_ 2
#define S_ 2048
#define E_ 2048
#define H_ 16
#define NOPE_ 64
#define ROPE_ 32
#define V_ 64
#define KVR_ 256
#define QKD_ 96
#define SCALE_ 0.10206207261596577f  /* 96^-0.5 */

typedef __hip_bfloat16 bf16;
typedef __attribute__((ext_vector_type(8))) short short8;
typedef __attribute__((ext_vector_type(4))) float floatx4;

__device__ __forceinline__ float bf2f(bf16 v) { return __bfloat162float(v); }
__device__ __forceinline__ short f2bf_s(float f) {
    bf16 h = __float2bfloat16(f);
    return *reinterpret_cast<short*>(&h);
}

// ---------------- fp32 -> bf16 conversion (8 elems/thread) ----------------
__global__ __launch_bounds__(256) void conv_bf16_kernel(const float* __restrict__ src,
                                                        bf16* __restrict__ dst, int n8) {
    int i = blockIdx.x * 256 + threadIdx.x;
    if (i >= n8) return;
    float4 a = ((const float4*)src)[2 * i];
    float4 b = ((const float4*)src)[2 * i + 1];
    short8 r;
    r[0] = f2bf_s(a.x); r[1] = f2bf_s(a.y); r[2] = f2bf_s(a.z); r[3] = f2bf_s(a.w);
    r[4] = f2bf_s(b.x); r[5] = f2bf_s(b.y); r[6] = f2bf_s(b.z); r[7] = f2bf_s(b.w);
    ((short8*)dst)[i] = r;
}

// ---------------- bf16 MFMA GEMM: C(M,N) fp32 = A(M,K) @ B(N,K)^T ----------------
// BM=BN=128, BK=32, 256 threads (4 waves, each 64x64). M%128==0, N%128==0, K%32==0.
__global__ __launch_bounds__(256, 2) void gemm_bt_mfma(const bf16* __restrict__ A,
                                                       const bf16* __restrict__ Bm,
                                                       float* __restrict__ C,
                                                       int M, int N, int K) {
    __shared__ bf16 As[128][40];  // +8 pad: breaks pow2 bank stride
    __shared__ bf16 Bs[128][40];
    int tid = threadIdx.x;
    int lane = tid & 63, w = tid >> 6;
    int q4 = lane >> 4, c16 = lane & 15;
    int wr = w >> 1, wc = w & 1;
    int m0 = blockIdx.y * 128, n0 = blockIdx.x * 128;
    floatx4 acc[4][4];
#pragma unroll
    for (int mi = 0; mi < 4; ++mi)
#pragma unroll
        for (int ni = 0; ni < 4; ++ni) acc[mi][ni] = (floatx4){0.f, 0.f, 0.f, 0.f};

    for (int k0 = 0; k0 < K; k0 += 32) {
#pragma unroll
        for (int i = 0; i < 2; ++i) {
            int id = tid + i * 256;
            int r = id >> 2, ck = id & 3;
            *(short8*)(void*)&As[r][ck * 8] =
                *(const short8*)(const void*)&A[(size_t)(m0 + r) * K + k0 + ck * 8];
            *(short8*)(void*)&Bs[r][ck * 8] =
                *(const short8*)(const void*)&Bm[(size_t)(n0 + r) * K + k0 + ck * 8];
        }
        __syncthreads();
        short8 af[4], bfr[4];
#pragma unroll
        for (int mi = 0; mi < 4; ++mi)
            af[mi] = *(const short8*)(const void*)&As[wr * 64 + mi * 16 + c16][q4 * 8];
#pragma unroll
        for (int ni = 0; ni < 4; ++ni)
            bfr[ni] = *(const short8*)(const void*)&Bs[wc * 64 + ni * 16 + c16][q4 * 8];
#pragma unroll
        for (int mi = 0; mi < 4; ++mi)
#pragma unroll
            for (int ni = 0; ni < 4; ++ni)
                acc[mi][ni] = __builtin_amdgcn_mfma_f32_16x16x32_bf16(af[mi], bfr[ni], acc[mi][ni], 0, 0, 0);
        __syncthreads();
    }
#pragma unroll
    for (int mi = 0; mi < 4; ++mi)
#pragma unroll
        for (int ni = 0; ni < 4; ++ni)
#pragma unroll
            for (int r = 0; r < 4; ++r) {
                int row = m0 + wr * 64 + mi * 16 + q4 * 4 + r;
                int col = n0 + wc * 64 + ni * 16 + c16;
                C[(size_t)row * N + col] = acc[mi][ni][r];
            }
}

// ---------------- fp32 tiled GEMM: C = A @ B^T (used for kv-proj, N=288) ----------------
__global__ __launch_bounds__(256) void gemm_tn(const float* __restrict__ A,
                                               const float* __restrict__ Bm,
                                               float* __restrict__ C,
                                               int M, int N, int K) {
    __shared__ float As[16][68];
    __shared__ float Bs[16][68];
    int tid = threadIdx.x;
    int tx = tid & 15, ty = tid >> 4;
    int m0 = blockIdx.y * 64, n0 = blockIdx.x * 64;
    float acc[4][4] = {};
    for (int k0 = 0; k0 < K; k0 += 16) {
#pragma unroll
        for (int it = 0; it < 4; ++it) {
            int idx = tid + it * 256;
            int r = idx >> 4, c = idx & 15;
            int m = m0 + r;
            As[c][r] = (m < M) ? A[(size_t)m * K + (k0 + c)] : 0.f;
            int n = n0 + r;
            Bs[c][r] = (n < N) ? Bm[(size_t)n * K + (k0 + c)] : 0.f;
        }
        __syncthreads();
#pragma unroll
        for (int kk = 0; kk < 16; ++kk) {
            float4 a = *(const float4*)&As[kk][ty * 4];
            float4 b = *(const float4*)&Bs[kk][tx * 4];
            acc[0][0] += a.x * b.x; acc[0][1] += a.x * b.y; acc[0][2] += a.x * b.z; acc[0][3] += a.x * b.w;
            acc[1][0] += a.y * b.x; acc[1][1] += a.y * b.y; acc[1][2] += a.y * b.z; acc[1][3] += a.y * b.w;
            acc[2][0] += a.z * b.x; acc[2][1] += a.z * b.y; acc[2][2] += a.z * b.z; acc[2][3] += a.z * b.w;
            acc[3][0] += a.w * b.x; acc[3][1] += a.w * b.y; acc[3][2] += a.w * b.z; acc[3][3] += a.w * b.w;
        }
        __syncthreads();
    }
#pragma unroll
    for (int i = 0; i < 4; ++i) {
        int m = m0 + ty * 4 + i;
        if (m >= M) continue;
#pragma unroll
        for (int j = 0; j < 4; ++j) {
            int n = n0 + tx * 4 + j;
            if (n < N) C[(size_t)m * N + n] = acc[i][j];
        }
    }
}

// ---------------- LayerNorm(kv_c) + RoPE(k_pe) (fp32) ----------------
__global__ __launch_bounds__(256) void ln_rope_kernel(const float* __restrict__ kvraw,
                                                      const float* __restrict__ g,
                                                      const float* __restrict__ bta,
                                                      float* __restrict__ kv_c,
                                                      float* __restrict__ kpe) {
    int r = blockIdx.x;
    int tid = threadIdx.x;
    int lane = tid & 63, w = tid >> 6;
    float x = kvraw[(size_t)r * 288 + tid];
    float v1 = x, v2 = x * x;
#pragma unroll
    for (int o = 32; o; o >>= 1) { v1 += __shfl_down(v1, o); v2 += __shfl_down(v2, o); }
    __shared__ float s1[4], s2[4], stats[2];
    if (lane == 0) { s1[w] = v1; s2[w] = v2; }
    __syncthreads();
    if (tid == 0) {
        float S1 = s1[0] + s1[1] + s1[2] + s1[3];
        float S2 = s2[0] + s2[1] + s2[2] + s2[3];
        float mean = S1 / 256.0f;
        float var = S2 / 256.0f - mean * mean;
        stats[0] = mean;
        stats[1] = rsqrtf(var + 1e-5f);
    }
    __syncthreads();
    float y = (x - stats[0]) * stats[1] * g[tid] + bta[tid];
    kv_c[(size_t)r * 256 + tid] = y;
    if (tid < 16) {
        int j = tid;
        int s = r & (S_ - 1);
        double freq = exp(-(double)(2 * j) * (9.210340371976184 / 32.0));
        double ang = (double)s * freq;
        float c = (float)cos(ang), sn = (float)sin(ang);
        float x0 = kvraw[(size_t)r * 288 + 256 + 2 * j];
        float x1 = kvraw[(size_t)r * 288 + 256 + 2 * j + 1];
        kpe[(size_t)r * 32 + 2 * j]     = x0 * c - x1 * sn;
        kpe[(size_t)r * 32 + 2 * j + 1] = x0 * sn + x1 * c;
    }
}

// ---------------- C2 / P2 ----------------
__global__ __launch_bounds__(64) void c2p2_kernel(const float* __restrict__ fcw_c,
                                                  const float* __restrict__ fcb_c,
                                                  const float* __restrict__ fcw_p,
                                                  const float* __restrict__ fcb_p,
                                                  float* __restrict__ C2,
                                                  float* __restrict__ P2) {
    int t = blockIdx.x;
    int k = threadIdx.x;
    __shared__ float Crow[256], Prow[256];
    for (int i = k; i < 128; i += 64) {
        double div = exp(-(double)i * (9.210340371976184 / 128.0));
        double ap = (double)t * div;
        Prow[2 * i]     = (float)sin(ap);
        Prow[2 * i + 1] = (float)cos(ap);
        double ac = (double)(t >> 1) * div;
        Crow[2 * i]     = (float)sin(ac);
        Crow[2 * i + 1] = (float)cos(ac);
    }
    __syncthreads();
    float sc = fcb_c[k], sp = fcb_p[k];
    for (int c = 0; c < 256; ++c) {
        sc += Crow[c] * fcw_c[(size_t)k * 256 + c];
        sp += Prow[c] * fcw_p[(size_t)k * 256 + c];
    }
    C2[(size_t)t * 64 + k] = sc;
    P2[(size_t)t * 64 + k] = sp;
}

__global__ __launch_bounds__(256) void gates_kernel(const float* __restrict__ C2,
                                                    const float* __restrict__ P2,
                                                    float* __restrict__ g0,
                                                    float* __restrict__ g1) {
    int t = blockIdx.x * 256 + threadIdx.x;
    if (t >= S_) return;
    float d0 = 0.f;
    for (int k = 0; k < 64; ++k) d0 += C2[(size_t)t * 64 + k] * P2[(size_t)t * 64 + k];
    g0[t] = 1.0f / (1.0f + expf(-d0));
    float gg = 0.f;
    if (t & 1) {
        float d1 = 0.f;
        for (int k = 0; k < 64; ++k) d1 += C2[(size_t)t * 64 + k] * P2[(size_t)(t - 1) * 64 + k];
        gg = 1.0f / (1.0f + expf(-d1));
    }
    g1[t] = gg;
}

// ---------------- gated kv_t / k_pe_t -> kve bf16 (b,s,288) ----------------
__global__ __launch_bounds__(256) void kve_kernel(const float* __restrict__ kv_c,
                                                  const float* __restrict__ kpe,
                                                  const float* __restrict__ g0,
                                                  const float* __restrict__ g1,
                                                  bf16* __restrict__ kve) {
    int r = blockIdx.x, tid = threadIdx.x;
    int t = r & (S_ - 1);
    float a = g0[t], bb = g1[t];
    float v = a * kv_c[(size_t)r * 256 + tid];
    if (t & 1) v += bb * kv_c[(size_t)(r - 1) * 256 + tid];
    kve[(size_t)r * 288 + tid] = __float2bfloat16(v);
    if (tid < 32) {
        float u = a * kpe[(size_t)r * 32 + tid];
        if (t & 1) u += bb * kpe[(size_t)(r - 1) * 32 + tid];
        kve[(size_t)r * 288 + 256 + tid] = __float2bfloat16(u);
    }
}

// ---------------- kveT[b][c][u] = kve[b][2u+1][c], c<256, row stride 1056 ----------------
__global__ __launch_bounds__(256) void kveT_kernel(const bf16* __restrict__ kve,
                                                   bf16* __restrict__ kveT) {
    int u0 = blockIdx.x * 64, c0 = blockIdx.y * 64, b = blockIdx.z;
    int tid = threadIdx.x;
    int c = c0 + (tid >> 2), ug = u0 + (tid & 3) * 16;
    const bf16* src = kve + (size_t)b * S_ * 288;
    short8 o0, o1;
#pragma unroll
    for (int k = 0; k < 8; ++k) o0[k] = *(const short*)&src[(size_t)(2 * (ug + k) + 1) * 288 + c];
#pragma unroll
    for (int k = 0; k < 8; ++k) o1[k] = *(const short*)&src[(size_t)(2 * (ug + 8 + k) + 1) * 288 + c];
    bf16* dst = kveT + (size_t)(b * 256 + c) * 1056 + ug;
    *(short8*)(void*)dst = o0;
    *(short8*)(void*)(dst + 8) = o1;
}

// ---------------- q_abs GEMM per head: qe[(m*16+h)*288 + c] = SCALE * q_nope @ W_nope ----
__global__ __launch_bounds__(256) void qabs_gemm_kernel(const float* __restrict__ q,
                                                        const float* __restrict__ wkv_b,
                                                        bf16* __restrict__ qe) {
    __shared__ float As[16][68], Bs[16][68];
    int tid = threadIdx.x;
    int tx = tid & 15, ty = tid >> 4;
    int n0 = blockIdx.x * 64, m0 = blockIdx.y * 64, h = blockIdx.z;
    float acc[4][4] = {};
    for (int k0 = 0; k0 < 64; k0 += 16) {
#pragma unroll
        for (int it = 0; it < 4; ++it) {
            int id = tid + it * 256;
            int r = id >> 4, c = id & 15;
            As[c][r] = q[(size_t)(m0 + r) * (H_ * QKD_) + h * QKD_ + k0 + c];
        }
#pragma unroll
        for (int it = 0; it < 4; ++it) {
            int id = tid + it * 256;
            int c = id >> 6, r = id & 63;
            Bs[c][r] = wkv_b[(size_t)(h * 128 + k0 + c) * 256 + n0 + r];
        }
        __syncthreads();
#pragma unroll
        for (int kk = 0; kk < 16; ++kk) {
            float4 a = *(const float4*)&As[kk][ty * 4];
            float4 b = *(const float4*)&Bs[kk][tx * 4];
            acc[0][0] += a.x * b.x; acc[0][1] += a.x * b.y; acc[0][2] += a.x * b.z; acc[0][3] += a.x * b.w;
            acc[1][0] += a.y * b.x; acc[1][1] += a.y * b.y; acc[1][2] += a.y * b.z; acc[1][3] += a.y * b.w;
            acc[2][0] += a.z * b.x; acc[2][1] += a.z * b.y; acc[2][2] += a.z * b.z; acc[2][3] += a.z * b.w;
            acc[3][0] += a.w * b.x; acc[3][1] += a.w * b.y; acc[3][2] += a.w * b.z; acc[3][3] += a.w * b.w;
        }
        __syncthreads();
    }
#pragma unroll
    for (int i = 0; i < 4; ++i)
#pragma unroll
        for (int j = 0; j < 4; ++j)
            qe[((size_t)(m0 + ty * 4 + i) * H_ + h) * 288 + n0 + tx * 4 + j] =
                __float2bfloat16(acc[i][j] * SCALE_);
}

// ---------------- roped, scaled q_pe -> qe[...,256:288] ----------------
__global__ __launch_bounds__(256) void rope_qe_kernel(const float* __restrict__ q,
                                                      bf16* __restrict__ qe) {
    int idx = blockIdx.x * 256 + threadIdx.x;
    if (idx >= B_ * S_ * H_ * 16) return;
    int j = idx & 15;
    int s = (idx >> 8) & (S_ - 1);
    double freq = exp(-(double)(2 * j) * (9.210340371976184 / 32.0));
    double ang = (double)s * freq;
    float c = (float)cos(ang), sn = (float)sin(ang);
    size_t row = idx >> 4;
    float x0 = q[row * QKD_ + NOPE_ + 2 * j];
    float x1 = q[row * QKD_ + NOPE_ + 2 * j + 1];
    qe[row * 288 + 256 + 2 * j]     = __float2bfloat16((x0 * c - x1 * sn) * SCALE_);
    qe[row * 288 + 256 + 2 * j + 1] = __float2bfloat16((x0 * sn + x1 * c) * SCALE_);
}

// ---------------- MFMA flash attention: one block per (b,s), all 16 heads ----------------
// scores(16h x 32keys) = Qe(16x288) @ Kve^T ; online softmax; x(16h x 256) += P @ kvt
__global__ __launch_bounds__(256, 2) void attn_mfma_kernel(const bf16* __restrict__ qe,
                                                           const bf16* __restrict__ kve,
                                                           const bf16* __restrict__ kveT,
                                                           bf16* __restrict__ xout) {
    int s = blockIdx.x, b = blockIdx.y;
    int tid = threadIdx.x;
    int lane = tid & 63, w = tid >> 6;
    int q4 = lane >> 4, c16 = lane & 15;

    __shared__ bf16 qes[16 * 288];
    __shared__ float ptile[4][16][36];
    __shared__ float xs[16][257];
    __shared__ float mw[4][16], lw[4][16];
    __shared__ float sred[16];
    __shared__ float gl[16];

    for (int i = tid; i < 16 * 257; i += 256) (&xs[0][0])[i] = 0.f;
    {
        const float4* src = (const float4*)(qe + (size_t)(b * S_ + s) * H_ * 288);
        float4* dst = (float4*)qes;
        for (int i = tid; i < 576; i += 256) dst[i] = src[i];
    }
    __syncthreads();

    short8 qf[9];
#pragma unroll
    for (int kk = 0; kk < 9; ++kk)
        qf[kk] = *(const short8*)(const void*)&qes[c16 * 288 + kk * 32 + q4 * 8];

    floatx4 acc[16];
#pragma unroll
    for (int n = 0; n < 16; ++n) acc[n] = (floatx4){0.f, 0.f, 0.f, 0.f};
    float m_i[4] = {-1e30f, -1e30f, -1e30f, -1e30f};
    float l_i[4] = {0.f, 0.f, 0.f, 0.f};

    int Nodd = (s + 1) >> 1;               // visible odd keys t=2u+1, u<Nodd
    int niter = (Nodd + 31) >> 5;
    const bf16* kveb = kve + (size_t)b * S_ * 288;
    const bf16* kvTb = kveT + (size_t)b * 256 * 1056;

    for (int it = w; it < niter; it += 4) {
        int u0 = it * 32;
        floatx4 sc[2];
#pragma unroll
        for (int g = 0; g < 2; ++g) {
            floatx4 cf = (floatx4){0.f, 0.f, 0.f, 0.f};
            int u = u0 + g * 16 + c16;
            int uc = u > 1023 ? 1023 : u;
            const bf16* krow = kveb + (size_t)(2 * uc + 1) * 288;
#pragma unroll
            for (int kk = 0; kk < 9; ++kk) {
                short8 bv = *(const short8*)(const void*)&krow[kk * 32 + q4 * 8];
                cf = __builtin_amdgcn_mfma_f32_16x16x32_bf16(qf[kk], bv, cf, 0, 0, 0);
            }
            if (u >= Nodd) { cf[0] = -1e30f; cf[1] = -1e30f; cf[2] = -1e30f; cf[3] = -1e30f; }
            sc[g] = cf;
        }
        float p0[4], p1[4];
#pragma unroll
        for (int r = 0; r < 4; ++r) {
            float tmax = fmaxf(sc[0][r], sc[1][r]);
            tmax = fmaxf(tmax, __shfl_xor(tmax, 1));
            tmax = fmaxf(tmax, __shfl_xor(tmax, 2));
            tmax = fmaxf(tmax, __shfl_xor(tmax, 4));
            tmax = fmaxf(tmax, __shfl_xor(tmax, 8));
            float mn = fmaxf(m_i[r], tmax);
            float al = __expf(m_i[r] - mn);
            p0[r] = __expf(sc[0][r] - mn);
            p1[r] = __expf(sc[1][r] - mn);
            float rs = p0[r] + p1[r];
            rs += __shfl_xor(rs, 1);
            rs += __shfl_xor(rs, 2);
            rs += __shfl_xor(rs, 4);
            rs += __shfl_xor(rs, 8);
            l_i[r] = l_i[r] * al + rs;
            m_i[r] = mn;
#pragma unroll
            for (int n = 0; n < 16; ++n) acc[n][r] *= al;
            ptile[w][q4 * 4 + r][c16]      = p0[r];
            ptile[w][q4 * 4 + r][16 + c16] = p1[r];
        }
        // P (C-layout) -> A-frag via per-wave LDS transpose
        short8 pf;
        {
            const float* pr = &ptile[w][c16][q4 * 8];
            float4 pa = *(const float4*)(pr);
            float4 pb = *(const float4*)(pr + 4);
            pf[0] = f2bf_s(pa.x); pf[1] = f2bf_s(pa.y); pf[2] = f2bf_s(pa.z); pf[3] = f2bf_s(pa.w);
            pf[4] = f2bf_s(pb.x); pf[5] = f2bf_s(pb.y); pf[6] = f2bf_s(pb.z); pf[7] = f2bf_s(pb.w);
        }
#pragma unroll
        for (int n = 0; n < 16; ++n) {
            short8 bv = *(const short8*)(const void*)&kvTb[(size_t)(n * 16 + c16) * 1056 + u0 + q4 * 8];
            acc[n] = __builtin_amdgcn_mfma_f32_16x16x32_bf16(pf, bv, acc[n], 0, 0, 0);
        }
    }

    // self key (t == s) for even s — wave 0 only, VALU
    if (w == 0 && ((s & 1) == 0)) {
        const bf16* srow = kveb + (size_t)s * 288;
        float d = 0.f;
        int e0 = q4 * 72;
        for (int e = 0; e < 72; ++e) d += bf2f(qes[c16 * 288 + e0 + e]) * bf2f(srow[e0 + e]);
        d += __shfl_xor(d, 16);
        d += __shfl_xor(d, 32);
        if (lane < 16) sred[lane] = d;
        float kvv[16];
#pragma unroll
        for (int n = 0; n < 16; ++n) kvv[n] = bf2f(srow[n * 16 + c16]);
#pragma unroll
        for (int r = 0; r < 4; ++r) {
            float scf = sred[q4 * 4 + r];
            float mn = fmaxf(m_i[r], scf);
            float al = __expf(m_i[r] - mn);
            float p = __expf(scf - mn);
            l_i[r] = l_i[r] * al + p;
            m_i[r] = mn;
#pragma unroll
            for (int n = 0; n < 16; ++n) acc[n][r] = acc[n][r] * al + p * kvv[n];
        }
    }

    // merge 4 waves
    if (c16 == 0) {
#pragma unroll
        for (int r = 0; r < 4; ++r) { mw[w][q4 * 4 + r] = m_i[r]; lw[w][q4 * 4 + r] = l_i[r]; }
    }
    __syncthreads();
    if (tid < 16) {
        float gm = fmaxf(fmaxf(mw[0][tid], mw[1][tid]), fmaxf(mw[2][tid], mw[3][tid]));
        gl[tid] = __expf(mw[0][tid] - gm) * lw[0][tid] + __expf(mw[1][tid] - gm) * lw[1][tid]
                + __expf(mw[2][tid] - gm) * lw[2][tid] + __expf(mw[3][tid] - gm) * lw[3][tid];
    }
    float ga[4];
#pragma unroll
    for (int r = 0; r < 4; ++r) {
        int h = q4 * 4 + r;
        float gm = fmaxf(fmaxf(mw[0][h], mw[1][h]), fmaxf(mw[2][h], mw[3][h]));
        ga[r] = __expf(m_i[r] - gm);
    }
#pragma unroll
    for (int n = 0; n < 16; ++n)
#pragma unroll
        for (int r = 0; r < 4; ++r)
            atomicAdd(&xs[q4 * 4 + r][n * 16 + c16], acc[n][r] * ga[r]);
    __syncthreads();
    {
        int h = tid >> 4, cb = (tid & 15) * 16;
        float invl = 1.f / gl[h];
        bf16* dst = xout + ((size_t)(b * S_ + s) * H_ + h) * 256 + cb;
        short8 o0, o1;
#pragma unroll
        for (int k = 0; k < 8; ++k) o0[k] = f2bf_s(xs[h][cb + k] * invl);
#pragma unroll
        for (int k = 0; k < 8; ++k) o1[k] = f2bf_s(xs[h][cb + 8 + k] * invl);
        *(short8*)(void*)dst = o0;
        *(short8*)(void*)(dst + 8) = o1;
    }
}

// ---------------- V-projection per head: outp[m, h*64+n] = x[m,h,:] @ Wv_h[n,:] ----------
__global__ __launch_bounds__(256) void vproj_kernel(const bf16* __restrict__ x,
                                                    const float* __restrict__ wkv_b,
                                                    bf16* __restrict__ outp) {
    __shared__ float As[16][68], Bs[16][68];
    int tid = threadIdx.x;
    int tx = tid & 15, ty = tid >> 4;
    int m0 = blockIdx.x * 64, h = blockIdx.y;
    float acc[4][4] = {};
    for (int k0 = 0; k0 < 256; k0 += 16) {
#pragma unroll
        for (int it = 0; it < 4; ++it) {
            int id = tid + it * 256;
            int r = id >> 4, c = id & 15;
            As[c][r] = bf2f(x[((size_t)(m0 + r) * H_ + h) * 256 + k0 + c]);
            Bs[c][r] = wkv_b[(size_t)(h * 128 + 64 + r) * 256 + k0 + c];
        }
        __syncthreads();
#pragma unroll
        for (int kk = 0; kk < 16; ++kk) {
            float4 a = *(const float4*)&As[kk][ty * 4];
            float4 b = *(const float4*)&Bs[kk][tx * 4];
            acc[0][0] += a.x * b.x; acc[0][1] += a.x * b.y; acc[0][2] += a.x * b.z; acc[0][3] += a.x * b.w;
            acc[1][0] += a.y * b.x; acc[1][1] += a.y * b.y; acc[1][2] += a.y * b.z; acc[1][3] += a.y * b.w;
            acc[2][0] += a.z * b.x; acc[2][1] += a.z * b.y; acc[2][2] += a.z * b.z; acc[2][3] += a.z * b.w;
            acc[3][0] += a.w * b.x; acc[3][1] += a.w * b.y; acc[3][2] += a.w * b.z; acc[3][3] += a.w * b.w;
        }
        __syncthreads();
    }
#pragma unroll
    for (int i = 0; i < 4; ++i)
#pragma unroll
        for (int j = 0; j < 4; ++j)
            outp[(size_t)(m0 + ty * 4 + i) * 1024 + h * 64 + tx * 4 + j] = __float2bfloat16(acc[i][j]);
}

extern "C" void kernel_launch(void* const* d_in, const int* in_sizes, int n_in,
                              void* d_out, int out_size, void* d_ws, size_t ws_size,
                              hipStream_t stream) {
    const float* hs     = (const float*)d_in[0];
    const float* wq     = (const float*)d_in[1];
    const float* wkv_a  = (const float*)d_in[2];
    const float* ln_g   = (const float*)d_in[3];
    const float* ln_b   = (const float*)d_in[4];
    const float* wkv_b  = (const float*)d_in[5];
    const float* wo     = (const float*)d_in[6];
    const float* fc_c_w = (const float*)d_in[7];
    const float* fc_c_b = (const float*)d_in[8];
    const float* fc_p_w = (const float*)d_in[9];
    const float* fc_p_b = (const float*)d_in[10];
    float* out = (float*)d_out;
    (void)in_sizes; (void)n_in; (void)out_size; (void)ws_size;

    const int M = B_ * S_;  // 4096
    char* wsb = (char*)d_ws;
    size_t o = 0;
    auto alloc = [&](size_t bytes) { char* p = wsb + o; o += (bytes + 255) & ~(size_t)255; return p; };

    // region 1: qe (37.75 MB) — front doubles as hs_bf (16.78 MB) + wq_bf (6.29 MB)
    bf16* qe    = (bf16*)alloc((size_t)M * H_ * 288 * 2);
    bf16* hs_bf = qe;                                    // dead after q-proj
    bf16* wq_bf = (bf16*)((char*)qe + (size_t)M * E_ * 2);
    // region 2: q fp32 (25.17 MB) then x_bf (33.55 MB)
    float* q    = (float*)alloc((size_t)M * H_ * 256 * 2);  // 33.55 MB region
    bf16*  x_bf = (bf16*)q;
    // region 3: kvraw fp32 (4.72 MB) then wo_bf (4.19 MB)
    float* kvraw = (float*)alloc((size_t)M * 288 * 4);
    bf16*  wo_bf = (bf16*)kvraw;
    float* kv_c = (float*)alloc((size_t)M * 256 * 4);
    float* kpe  = (float*)alloc((size_t)M * 32 * 4);
    float* C2   = (float*)alloc((size_t)S_ * 64 * 4);
    float* P2   = (float*)alloc((size_t)S_ * 64 * 4);
    float* g0   = (float*)alloc(S_ * 4);
    float* g1   = (float*)alloc(S_ * 4);
    bf16* kve   = (bf16*)alloc((size_t)M * 288 * 2);
    bf16* kveT  = (bf16*)alloc((size_t)B_ * 256 * 1056 * 2);
    bf16* outp_bf = (bf16*)alloc((size_t)M * 1024 * 2);

    // 1) convert hs, wq to bf16
    conv_bf16_kernel<<<(M * E_ / 8 + 255) / 256, 256, 0, stream>>>(hs, hs_bf, M * E_ / 8);
    conv_bf16_kernel<<<(1536 * E_ / 8 + 255) / 256, 256, 0, stream>>>(wq, wq_bf, 1536 * E_ / 8);
    // 2) q = hs @ wq.T  (MFMA)
    gemm_bt_mfma<<<dim3(1536 / 128, M / 128), 256, 0, stream>>>(hs_bf, wq_bf, q, M, 1536, E_);
    // 3) kv = hs @ wkv_a.T (fp32 VALU, N=288)
    gemm_tn<<<dim3(5, M / 64), 256, 0, stream>>>(hs, wkv_a, kvraw, M, KVR_ + ROPE_, E_);
    // 4) LayerNorm + k_pe RoPE
    ln_rope_kernel<<<M, 256, 0, stream>>>(kvraw, ln_g, ln_b, kv_c, kpe);
    // 5) convert wo (reuses kvraw region — kvraw dead now)
    conv_bf16_kernel<<<(2048 * 1024 / 8 + 255) / 256, 256, 0, stream>>>(wo, wo_bf, 2048 * 1024 / 8);
    // 6) gates
    c2p2_kernel<<<S_, 64, 0, stream>>>(fc_c_w, fc_c_b, fc_p_w, fc_p_b, C2, P2);
    gates_kernel<<<(S_ + 255) / 256, 256, 0, stream>>>(C2, P2, g0, g1);
    // 7) kve bf16
    kve_kernel<<<M, 256, 0, stream>>>(kv_c, kpe, g0, g1, kve);
    // 8) kveT
    kveT_kernel<<<dim3(16, 4, B_), 256, 0, stream>>>(kve, kveT);
    // 9) q_abs -> qe[:, :256] (overwrites hs_bf/wq_bf region — both dead)
    qabs_gemm_kernel<<<dim3(4, M / 64, H_), 256, 0, stream>>>(q, wkv_b, qe);
    // 10) roped q_pe -> qe[:, 256:288]
    rope_qe_kernel<<<(M * H_ * 16 + 255) / 256, 256, 0, stream>>>(q, qe);
    // 11) attention (q region dead -> x_bf alias)
    attn_mfma_kernel<<<dim3(S_, B_), 256, 0, stream>>>(qe, kve, kveT, x_bf);
    // 12) V-projection
    vproj_kernel<<<dim3(M / 64, H_), 256, 0, stream>>>(x_bf, wkv_b, outp_bf);
    // 13) out = outp @ wo.T (MFMA)
    gemm_bt_mfma<<<dim3(E_ / 128, M / 128), 256, 0, stream>>>(outp_bf, wo_bf, out, M, E_, 1024);
}

// Round 4
// 477.779 us; speedup vs baseline: 8.2356x; 2.4415x over previous
//
#include <hip/hip_runtime.h>
#include <hip/hip_bf16.h>
#include <math.h>

#define B_ 2
#define S_ 2048
#define E_ 2048
#define H_ 16
#define NOPE_ 64
#define ROPE_ 32
#define V_ 64
#define KVR_ 256
#define QKD_ 96
#define SCALE_ 0.10206207261596577f  /* 96^-0.5 */

typedef __hip_bfloat16 bf16;
typedef __attribute__((ext_vector_type(8))) short short8;
typedef __attribute__((ext_vector_type(4))) float floatx4;

__device__ __forceinline__ float bf2f(bf16 v) { return __bfloat162float(v); }
__device__ __forceinline__ short f2bf_s(float f) {
    bf16 h = __float2bfloat16(f);
    return *reinterpret_cast<short*>(&h);
}
__device__ __forceinline__ void store_c(float* C, size_t i, float v) { C[i] = v; }
__device__ __forceinline__ void store_c(bf16* C, size_t i, float v) { C[i] = __float2bfloat16(v); }

// ---------------- fp32 -> bf16 conversion (8 elems/thread) ----------------
__global__ __launch_bounds__(256) void conv_bf16_kernel(const float* __restrict__ src,
                                                        bf16* __restrict__ dst, int n8) {
    int i = blockIdx.x * 256 + threadIdx.x;
    if (i >= n8) return;
    float4 a = ((const float4*)src)[2 * i];
    float4 b = ((const float4*)src)[2 * i + 1];
    short8 r;
    r[0] = f2bf_s(a.x); r[1] = f2bf_s(a.y); r[2] = f2bf_s(a.z); r[3] = f2bf_s(a.w);
    r[4] = f2bf_s(b.x); r[5] = f2bf_s(b.y); r[6] = f2bf_s(b.z); r[7] = f2bf_s(b.w);
    ((short8*)dst)[i] = r;
}

// ---------------- wkv_a (288x2048 fp32) -> zero-padded bf16 (384x2048) ----------------
__global__ __launch_bounds__(256) void conv_pad_wkva_kernel(const float* __restrict__ src,
                                                            bf16* __restrict__ dst) {
    int i = blockIdx.x * 256 + threadIdx.x;  // chunk of 8, 384*2048/8 total
    if (i >= 384 * 2048 / 8) return;
    int row = i >> 8;
    short8 r;
    if (row < 288) {
        float4 a = ((const float4*)src)[2 * i];
        float4 b = ((const float4*)src)[2 * i + 1];
        r[0] = f2bf_s(a.x); r[1] = f2bf_s(a.y); r[2] = f2bf_s(a.z); r[3] = f2bf_s(a.w);
        r[4] = f2bf_s(b.x); r[5] = f2bf_s(b.y); r[6] = f2bf_s(b.z); r[7] = f2bf_s(b.w);
    } else {
        for (int j = 0; j < 8; ++j) r[j] = 0;
    }
    ((short8*)dst)[i] = r;
}

// ---------------- wkvbT[h][c][d] = bf16(wkv_b[h*128+d][c]), d<64 ----------------
__global__ __launch_bounds__(256) void transpose_wkvbT_kernel(const float* __restrict__ wkv_b,
                                                              bf16* __restrict__ wkvbT) {
    int h = blockIdx.x, c = threadIdx.x;
#pragma unroll
    for (int d0 = 0; d0 < 64; d0 += 8) {
        short8 v;
#pragma unroll
        for (int j = 0; j < 8; ++j) v[j] = f2bf_s(wkv_b[(size_t)(h * 128 + d0 + j) * 256 + c]);
        *(short8*)(void*)&wkvbT[((size_t)h * 256 + c) * 64 + d0] = v;
    }
}

// ---------------- bf16 MFMA GEMM: C(M,N) = A(M,K) @ B(N,K)^T ----------------
// BM=BN=128, BK=32, 256 threads. M%128==0, N%128==0, K%32==0.
template <typename TC>
__global__ __launch_bounds__(256, 2) void gemm_bt_mfma(const bf16* __restrict__ A,
                                                       const bf16* __restrict__ Bm,
                                                       TC* __restrict__ C,
                                                       int M, int N, int K) {
    __shared__ bf16 As[128][40];
    __shared__ bf16 Bs[128][40];
    int tid = threadIdx.x;
    int lane = tid & 63, w = tid >> 6;
    int q4 = lane >> 4, c16 = lane & 15;
    int wr = w >> 1, wc = w & 1;
    int m0 = blockIdx.y * 128, n0 = blockIdx.x * 128;
    floatx4 acc[4][4];
#pragma unroll
    for (int mi = 0; mi < 4; ++mi)
#pragma unroll
        for (int ni = 0; ni < 4; ++ni) acc[mi][ni] = (floatx4){0.f, 0.f, 0.f, 0.f};

    for (int k0 = 0; k0 < K; k0 += 32) {
#pragma unroll
        for (int i = 0; i < 2; ++i) {
            int id = tid + i * 256;
            int r = id >> 2, ck = id & 3;
            *(short8*)(void*)&As[r][ck * 8] =
                *(const short8*)(const void*)&A[(size_t)(m0 + r) * K + k0 + ck * 8];
            *(short8*)(void*)&Bs[r][ck * 8] =
                *(const short8*)(const void*)&Bm[(size_t)(n0 + r) * K + k0 + ck * 8];
        }
        __syncthreads();
        short8 af[4], bfr[4];
#pragma unroll
        for (int mi = 0; mi < 4; ++mi)
            af[mi] = *(const short8*)(const void*)&As[wr * 64 + mi * 16 + c16][q4 * 8];
#pragma unroll
        for (int ni = 0; ni < 4; ++ni)
            bfr[ni] = *(const short8*)(const void*)&Bs[wc * 64 + ni * 16 + c16][q4 * 8];
#pragma unroll
        for (int mi = 0; mi < 4; ++mi)
#pragma unroll
            for (int ni = 0; ni < 4; ++ni)
                acc[mi][ni] = __builtin_amdgcn_mfma_f32_16x16x32_bf16(af[mi], bfr[ni], acc[mi][ni], 0, 0, 0);
        __syncthreads();
    }
#pragma unroll
    for (int mi = 0; mi < 4; ++mi)
#pragma unroll
        for (int ni = 0; ni < 4; ++ni)
#pragma unroll
            for (int r = 0; r < 4; ++r) {
                int row = m0 + wr * 64 + mi * 16 + q4 * 4 + r;
                int col = n0 + wc * 64 + ni * 16 + c16;
                store_c(C, (size_t)row * N + col, acc[mi][ni][r]);
            }
}

// ---------------- small-N strided/batched bf16 MFMA GEMM: BM=BN=64, BK=32 ----------------
// C[m][n] = scale * sum_k A[m][k]*B[n][k]; batch z applies element offsets.
template <typename TC>
__global__ __launch_bounds__(256, 2) void gemm64_mfma(const bf16* __restrict__ A, int lda, int aoffz,
                                                      const bf16* __restrict__ Bm, int ldb, int boffz,
                                                      TC* __restrict__ C, int ldc, int coffz,
                                                      int K, float scale) {
    int z = blockIdx.z;
    A += (size_t)z * aoffz;
    Bm += (size_t)z * boffz;
    C += (size_t)z * coffz;
    __shared__ bf16 As[64][40];
    __shared__ bf16 Bs[64][40];
    int tid = threadIdx.x;
    int lane = tid & 63, w = tid >> 6;
    int q4 = lane >> 4, c16 = lane & 15;
    int m0 = blockIdx.y * 64, n0 = blockIdx.x * 64;
    floatx4 acc[4];
#pragma unroll
    for (int ni = 0; ni < 4; ++ni) acc[ni] = (floatx4){0.f, 0.f, 0.f, 0.f};
    int r = tid >> 2, ck = tid & 3;
    for (int k0 = 0; k0 < K; k0 += 32) {
        *(short8*)(void*)&As[r][ck * 8] =
            *(const short8*)(const void*)&A[(size_t)(m0 + r) * lda + k0 + ck * 8];
        *(short8*)(void*)&Bs[r][ck * 8] =
            *(const short8*)(const void*)&Bm[(size_t)(n0 + r) * ldb + k0 + ck * 8];
        __syncthreads();
        short8 af = *(const short8*)(const void*)&As[w * 16 + c16][q4 * 8];
#pragma unroll
        for (int ni = 0; ni < 4; ++ni) {
            short8 bfr = *(const short8*)(const void*)&Bs[ni * 16 + c16][q4 * 8];
            acc[ni] = __builtin_amdgcn_mfma_f32_16x16x32_bf16(af, bfr, acc[ni], 0, 0, 0);
        }
        __syncthreads();
    }
#pragma unroll
    for (int ni = 0; ni < 4; ++ni)
#pragma unroll
        for (int rr = 0; rr < 4; ++rr)
            store_c(C, (size_t)(m0 + w * 16 + q4 * 4 + rr) * ldc + n0 + ni * 16 + c16,
                    acc[ni][rr] * scale);
}

// ---------------- LayerNorm(kv_c) + RoPE(k_pe); input stride 384 ----------------
__global__ __launch_bounds__(256) void ln_rope_kernel(const float* __restrict__ kvraw,
                                                      const float* __restrict__ g,
                                                      const float* __restrict__ bta,
                                                      float* __restrict__ kv_c,
                                                      float* __restrict__ kpe) {
    int r = blockIdx.x;
    int tid = threadIdx.x;
    int lane = tid & 63, w = tid >> 6;
    float x = kvraw[(size_t)r * 384 + tid];
    float v1 = x, v2 = x * x;
#pragma unroll
    for (int o = 32; o; o >>= 1) { v1 += __shfl_down(v1, o); v2 += __shfl_down(v2, o); }
    __shared__ float s1[4], s2[4], stats[2];
    if (lane == 0) { s1[w] = v1; s2[w] = v2; }
    __syncthreads();
    if (tid == 0) {
        float S1 = s1[0] + s1[1] + s1[2] + s1[3];
        float S2 = s2[0] + s2[1] + s2[2] + s2[3];
        float mean = S1 / 256.0f;
        float var = S2 / 256.0f - mean * mean;
        stats[0] = mean;
        stats[1] = rsqrtf(var + 1e-5f);
    }
    __syncthreads();
    float y = (x - stats[0]) * stats[1] * g[tid] + bta[tid];
    kv_c[(size_t)r * 256 + tid] = y;
    if (tid < 16) {
        int j = tid;
        int s = r & (S_ - 1);
        double freq = exp(-(double)(2 * j) * (9.210340371976184 / 32.0));
        double ang = (double)s * freq;
        float c = (float)cos(ang), sn = (float)sin(ang);
        float x0 = kvraw[(size_t)r * 384 + 256 + 2 * j];
        float x1 = kvraw[(size_t)r * 384 + 256 + 2 * j + 1];
        kpe[(size_t)r * 32 + 2 * j]     = x0 * c - x1 * sn;
        kpe[(size_t)r * 32 + 2 * j + 1] = x0 * sn + x1 * c;
    }
}

// ---------------- C2 / P2 ----------------
__global__ __launch_bounds__(64) void c2p2_kernel(const float* __restrict__ fcw_c,
                                                  const float* __restrict__ fcb_c,
                                                  const float* __restrict__ fcw_p,
                                                  const float* __restrict__ fcb_p,
                                                  float* __restrict__ C2,
                                                  float* __restrict__ P2) {
    int t = blockIdx.x;
    int k = threadIdx.x;
    __shared__ float Crow[256], Prow[256];
    for (int i = k; i < 128; i += 64) {
        double div = exp(-(double)i * (9.210340371976184 / 128.0));
        double ap = (double)t * div;
        Prow[2 * i]     = (float)sin(ap);
        Prow[2 * i + 1] = (float)cos(ap);
        double ac = (double)(t >> 1) * div;
        Crow[2 * i]     = (float)sin(ac);
        Crow[2 * i + 1] = (float)cos(ac);
    }
    __syncthreads();
    float sc = fcb_c[k], sp = fcb_p[k];
    for (int c = 0; c < 256; ++c) {
        sc += Crow[c] * fcw_c[(size_t)k * 256 + c];
        sp += Prow[c] * fcw_p[(size_t)k * 256 + c];
    }
    C2[(size_t)t * 64 + k] = sc;
    P2[(size_t)t * 64 + k] = sp;
}

__global__ __launch_bounds__(256) void gates_kernel(const float* __restrict__ C2,
                                                    const float* __restrict__ P2,
                                                    float* __restrict__ g0,
                                                    float* __restrict__ g1) {
    int t = blockIdx.x * 256 + threadIdx.x;
    if (t >= S_) return;
    float d0 = 0.f;
    for (int k = 0; k < 64; ++k) d0 += C2[(size_t)t * 64 + k] * P2[(size_t)t * 64 + k];
    g0[t] = 1.0f / (1.0f + expf(-d0));
    float gg = 0.f;
    if (t & 1) {
        float d1 = 0.f;
        for (int k = 0; k < 64; ++k) d1 += C2[(size_t)t * 64 + k] * P2[(size_t)(t - 1) * 64 + k];
        gg = 1.0f / (1.0f + expf(-d1));
    }
    g1[t] = gg;
}

// ---------------- gated kv_t -> kve_full bf16 [B*S][288] + packed odd kvo [B][1024][296] ---
__global__ __launch_bounds__(256) void kve_kernel(const float* __restrict__ kv_c,
                                                  const float* __restrict__ kpe,
                                                  const float* __restrict__ g0,
                                                  const float* __restrict__ g1,
                                                  bf16* __restrict__ kve_full,
                                                  bf16* __restrict__ kvo) {
    int r = blockIdx.x, tid = threadIdx.x;
    int b = r >> 11, t = r & (S_ - 1);
    float a = g0[t], bb = g1[t];
    float v = a * kv_c[(size_t)r * 256 + tid];
    if (t & 1) v += bb * kv_c[(size_t)(r - 1) * 256 + tid];
    bf16 vb = __float2bfloat16(v);
    kve_full[(size_t)r * 288 + tid] = vb;
    if (t & 1) kvo[((size_t)b * 1024 + (t >> 1)) * 296 + tid] = vb;
    if (tid < 32) {
        float u = a * kpe[(size_t)r * 32 + tid];
        if (t & 1) u += bb * kpe[(size_t)(r - 1) * 32 + tid];
        bf16 ub = __float2bfloat16(u);
        kve_full[(size_t)r * 288 + 256 + tid] = ub;
        if (t & 1) kvo[((size_t)b * 1024 + (t >> 1)) * 296 + 256 + tid] = ub;
    }
}

// ---------------- kvoT[b][c][u] = kvo[b][u][c], c<256, u<1024 ----------------
__global__ __launch_bounds__(256) void kvoT_kernel(const bf16* __restrict__ kvo,
                                                   bf16* __restrict__ kvoT) {
    int u0 = blockIdx.x * 64, c0 = blockIdx.y * 64, b = blockIdx.z;
    int tid = threadIdx.x;
    int c = c0 + (tid >> 2), ug = u0 + (tid & 3) * 16;
    const bf16* src = kvo + (size_t)b * 1024 * 296;
    short8 o0, o1;
#pragma unroll
    for (int k = 0; k < 8; ++k) o0[k] = *(const short*)&src[(size_t)(ug + k) * 296 + c];
#pragma unroll
    for (int k = 0; k < 8; ++k) o1[k] = *(const short*)&src[(size_t)(ug + 8 + k) * 296 + c];
    bf16* dst = kvoT + ((size_t)b * 256 + c) * 1024 + ug;
    *(short8*)(void*)dst = o0;
    *(short8*)(void*)(dst + 8) = o1;
}

// ---------------- roped, scaled q_pe -> qe[...,256:288) (bf16 input) ----------------
__global__ __launch_bounds__(256) void rope_qe_kernel(const bf16* __restrict__ q,
                                                      bf16* __restrict__ qe) {
    int idx = blockIdx.x * 256 + threadIdx.x;
    if (idx >= B_ * S_ * H_ * 16) return;
    int j = idx & 15;
    int s = (idx >> 8) & (S_ - 1);
    double freq = exp(-(double)(2 * j) * (9.210340371976184 / 32.0));
    double ang = (double)s * freq;
    float c = (float)cos(ang), sn = (float)sin(ang);
    size_t row = idx >> 4;
    float x0 = bf2f(q[row * (H_ * QKD_ / H_) * H_ / H_ + 0]);  // placeholder avoided below
    (void)x0;
    float a0 = bf2f(q[row * QKD_ + NOPE_ + 2 * j]);
    float a1 = bf2f(q[row * QKD_ + NOPE_ + 2 * j + 1]);
    qe[row * 288 + 256 + 2 * j]     = __float2bfloat16((a0 * c - a1 * sn) * SCALE_);
    qe[row * 288 + 256 + 2 * j + 1] = __float2bfloat16((a0 * sn + a1 * c) * SCALE_);
}

// ---------------- self scores: sscore[b][s][h] = qe[b,s,h,:] . kve_full[b,s,:] ----------
__global__ __launch_bounds__(256) void sscore_kernel(const bf16* __restrict__ qe,
                                                     const bf16* __restrict__ kve_full,
                                                     float* __restrict__ sscore) {
    int s = blockIdx.x, b = blockIdx.y;
    int tid = threadIdx.x;
    int h = tid >> 4, p = tid & 15;
    const bf16* qrow = qe + ((size_t)(b * S_ + s) * H_ + h) * 288;
    const bf16* krow = kve_full + (size_t)(b * S_ + s) * 288;
    float d = 0.f;
#pragma unroll
    for (int e = 0; e < 18; ++e) d += bf2f(qrow[p * 18 + e]) * bf2f(krow[p * 18 + e]);
    d += __shfl_xor(d, 1);
    d += __shfl_xor(d, 2);
    d += __shfl_xor(d, 4);
    d += __shfl_xor(d, 8);
    if (p == 0) sscore[((size_t)(b * S_ + s)) * H_ + h] = d;
}

// ---------------- flash attention: block = (b, 4 consecutive s); wave w owns s0+w --------
__global__ __launch_bounds__(256, 2) void attn2_kernel(const bf16* __restrict__ qe,
                                                       const bf16* __restrict__ kvo,
                                                       const bf16* __restrict__ kvoT,
                                                       const bf16* __restrict__ kve_full,
                                                       const float* __restrict__ sscore,
                                                       bf16* __restrict__ xout) {
    int s0 = (int)(gridDim.x - 1 - blockIdx.x) * 4;  // biggest blocks first
    int b = blockIdx.y;
    int tid = threadIdx.x;
    int lane = tid & 63, w = tid >> 6;
    int q4 = lane >> 4, c16 = lane & 15;
    int s = s0 + w;
    int Nodd = (s + 1) >> 1;

    __shared__ bf16 kvos[32][296];    // score B tile (18944 B)
    __shared__ bf16 kvoTs[256][40];   // PV B tile    (20480 B)
    __shared__ bf16 pt[4][16][40];    // per-wave P transpose (5120 B)
    __shared__ bf16 selfr[4][264];    // self-key rows (2112 B)

    if (tid < 128) {
        int rr = tid >> 5, ch = tid & 31;
        *(short8*)(void*)&selfr[rr][ch * 8] =
            *(const short8*)(const void*)&kve_full[(size_t)(b * S_ + s0 + rr) * 288 + ch * 8];
    }

    short8 qf[9];
    const bf16* qrow = qe + ((size_t)(b * S_ + s) * H_ + c16) * 288;
#pragma unroll
    for (int kk = 0; kk < 9; ++kk)
        qf[kk] = *(const short8*)(const void*)&qrow[kk * 32 + q4 * 8];

    floatx4 acc[16];
#pragma unroll
    for (int n = 0; n < 16; ++n) acc[n] = (floatx4){0.f, 0.f, 0.f, 0.f};
    float m_i[4] = {-1e30f, -1e30f, -1e30f, -1e30f};
    float l_i[4] = {0.f, 0.f, 0.f, 0.f};

    int niterB = (((s0 + 4) >> 1) + 31) >> 5;
    const bf16* kvob = kvo + (size_t)b * 1024 * 296;
    const bf16* kvoTb = kvoT + (size_t)b * 256 * 1024;

    for (int it = 0; it < niterB; ++it) {
        int u0 = it * 32;
        __syncthreads();  // previous iteration's LDS reads done
        {
            const short8* src = (const short8*)(const void*)(kvob + (size_t)u0 * 296);
            short8* dst = (short8*)(void*)&kvos[0][0];
            for (int i = tid; i < 1184; i += 256) dst[i] = src[i];
            for (int i = tid; i < 1024; i += 256) {
                int c = i >> 2, ch = i & 3;
                *(short8*)(void*)&kvoTs[c][ch * 8] =
                    *(const short8*)(const void*)&kvoTb[(size_t)c * 1024 + u0 + ch * 8];
            }
        }
        __syncthreads();

        floatx4 sc[2];
#pragma unroll
        for (int g = 0; g < 2; ++g) {
            floatx4 cf = (floatx4){0.f, 0.f, 0.f, 0.f};
#pragma unroll
            for (int kk = 0; kk < 9; ++kk) {
                short8 bv = *(const short8*)(const void*)&kvos[g * 16 + c16][kk * 32 + q4 * 8];
                cf = __builtin_amdgcn_mfma_f32_16x16x32_bf16(qf[kk], bv, cf, 0, 0, 0);
            }
            int u = u0 + g * 16 + c16;
            if (u >= Nodd) { cf[0] = -1e30f; cf[1] = -1e30f; cf[2] = -1e30f; cf[3] = -1e30f; }
            sc[g] = cf;
        }
#pragma unroll
        for (int r = 0; r < 4; ++r) {
            float tmax = fmaxf(sc[0][r], sc[1][r]);
            tmax = fmaxf(tmax, __shfl_xor(tmax, 1));
            tmax = fmaxf(tmax, __shfl_xor(tmax, 2));
            tmax = fmaxf(tmax, __shfl_xor(tmax, 4));
            tmax = fmaxf(tmax, __shfl_xor(tmax, 8));
            float mn = fmaxf(m_i[r], tmax);
            float al = __expf(m_i[r] - mn);
            float p0 = __expf(sc[0][r] - mn);
            float p1 = __expf(sc[1][r] - mn);
            float rs = p0 + p1;
            rs += __shfl_xor(rs, 1);
            rs += __shfl_xor(rs, 2);
            rs += __shfl_xor(rs, 4);
            rs += __shfl_xor(rs, 8);
            l_i[r] = l_i[r] * al + rs;
            m_i[r] = mn;
#pragma unroll
            for (int n = 0; n < 16; ++n) acc[n][r] *= al;
            pt[w][q4 * 4 + r][c16] = __float2bfloat16(p0);
            pt[w][q4 * 4 + r][16 + c16] = __float2bfloat16(p1);
        }
        short8 pf = *(const short8*)(const void*)&pt[w][c16][q4 * 8];
#pragma unroll
        for (int n = 0; n < 16; ++n) {
            short8 bv = *(const short8*)(const void*)&kvoTs[n * 16 + c16][q4 * 8];
            acc[n] = __builtin_amdgcn_mfma_f32_16x16x32_bf16(pf, bv, acc[n], 0, 0, 0);
        }
    }

    // self key (even s only; odd s's self is already in the odd set)
    if ((s & 1) == 0) {
#pragma unroll
        for (int r = 0; r < 4; ++r) {
            float scs = sscore[((size_t)(b * S_ + s)) * H_ + q4 * 4 + r];
            float mn = fmaxf(m_i[r], scs);
            float al = __expf(m_i[r] - mn);
            float p = __expf(scs - mn);
            l_i[r] = l_i[r] * al + p;
            m_i[r] = mn;
#pragma unroll
            for (int n = 0; n < 16; ++n)
                acc[n][r] = acc[n][r] * al + p * bf2f(selfr[w][n * 16 + c16]);
        }
    }

#pragma unroll
    for (int r = 0; r < 4; ++r) {
        float invl = 1.0f / l_i[r];
        bf16* orow = xout + ((size_t)(b * S_ + s) * H_ + q4 * 4 + r) * 256;
#pragma unroll
        for (int n = 0; n < 16; ++n)
            orow[n * 16 + c16] = __float2bfloat16(acc[n][r] * invl);
    }
}

extern "C" void kernel_launch(void* const* d_in, const int* in_sizes, int n_in,
                              void* d_out, int out_size, void* d_ws, size_t ws_size,
                              hipStream_t stream) {
    const float* hs     = (const float*)d_in[0];
    const float* wq     = (const float*)d_in[1];
    const float* wkv_a  = (const float*)d_in[2];
    const float* ln_g   = (const float*)d_in[3];
    const float* ln_b   = (const float*)d_in[4];
    const float* wkv_b  = (const float*)d_in[5];
    const float* wo     = (const float*)d_in[6];
    const float* fc_c_w = (const float*)d_in[7];
    const float* fc_c_b = (const float*)d_in[8];
    const float* fc_p_w = (const float*)d_in[9];
    const float* fc_p_b = (const float*)d_in[10];
    float* out = (float*)d_out;
    (void)in_sizes; (void)n_in; (void)out_size; (void)ws_size;

    const int M = B_ * S_;  // 4096
    char* wsb = (char*)d_ws;
    size_t o = 0;
    auto alloc = [&](size_t bytes) { char* p = wsb + o; o += (bytes + 255) & ~(size_t)255; return p; };

    bf16* qe = (bf16*)alloc((size_t)M * H_ * 288 * 2);                 // 37.75 MB
    // region2 (33.55 MB): phase a = hs_bf + wq_bf + wkva_pad; phase b = x_bf
    char* region2 = alloc((size_t)M * H_ * 256 * 2);
    bf16* hs_bf    = (bf16*)region2;
    bf16* wq_bf    = (bf16*)(region2 + (size_t)M * E_ * 2);
    bf16* wkva_pad = (bf16*)(region2 + (size_t)M * E_ * 2 + (size_t)1536 * E_ * 2);
    bf16* x_bf     = (bf16*)region2;
    // region3 (12.58 MB): q_bf, later outp_bf
    char* region3 = alloc((size_t)M * 1536 * 2);
    bf16* q_bf    = (bf16*)region3;
    bf16* outp_bf = (bf16*)region3;
    float* kvraw = (float*)alloc((size_t)M * 384 * 4);
    float* kv_c  = (float*)alloc((size_t)M * 256 * 4);
    float* kpe   = (float*)alloc((size_t)M * 32 * 4);
    bf16* wo_bf   = (bf16*)alloc((size_t)E_ * 1024 * 2);
    bf16* wkvb_bf = (bf16*)alloc((size_t)2048 * 256 * 2);
    bf16* wkvbT   = (bf16*)alloc((size_t)H_ * 256 * 64 * 2);
    bf16* kve_full = (bf16*)alloc((size_t)M * 288 * 2);
    bf16* kvo      = (bf16*)alloc((size_t)B_ * 1024 * 296 * 2);
    bf16* kvoT     = (bf16*)alloc((size_t)B_ * 256 * 1024 * 2);
    float* sscore  = (float*)alloc((size_t)M * H_ * 4);
    float* C2 = (float*)alloc((size_t)S_ * 64 * 4);
    float* P2 = (float*)alloc((size_t)S_ * 64 * 4);
    float* g0 = (float*)alloc(S_ * 4);
    float* g1 = (float*)alloc(S_ * 4);

    // conversions
    conv_bf16_kernel<<<(M * E_ / 8 + 255) / 256, 256, 0, stream>>>(hs, hs_bf, M * E_ / 8);
    conv_bf16_kernel<<<(1536 * E_ / 8 + 255) / 256, 256, 0, stream>>>(wq, wq_bf, 1536 * E_ / 8);
    conv_bf16_kernel<<<(E_ * 1024 / 8 + 255) / 256, 256, 0, stream>>>(wo, wo_bf, E_ * 1024 / 8);
    conv_bf16_kernel<<<(2048 * 256 / 8 + 255) / 256, 256, 0, stream>>>(wkv_b, wkvb_bf, 2048 * 256 / 8);
    conv_pad_wkva_kernel<<<(384 * 2048 / 8 + 255) / 256, 256, 0, stream>>>(wkv_a, wkva_pad);
    transpose_wkvbT_kernel<<<H_, 256, 0, stream>>>(wkv_b, wkvbT);
    // projections
    gemm_bt_mfma<bf16><<<dim3(1536 / 128, M / 128), 256, 0, stream>>>(hs_bf, wq_bf, q_bf, M, 1536, E_);
    gemm_bt_mfma<float><<<dim3(384 / 128, M / 128), 256, 0, stream>>>(hs_bf, wkva_pad, kvraw, M, 384, E_);
    // LN + k_pe rope
    ln_rope_kernel<<<M, 256, 0, stream>>>(kvraw, ln_g, ln_b, kv_c, kpe);
    // gates
    c2p2_kernel<<<S_, 64, 0, stream>>>(fc_c_w, fc_c_b, fc_p_w, fc_p_b, C2, P2);
    gates_kernel<<<(S_ + 255) / 256, 256, 0, stream>>>(C2, P2, g0, g1);
    // kve (full + packed odd) and transpose
    kve_kernel<<<M, 256, 0, stream>>>(kv_c, kpe, g0, g1, kve_full, kvo);
    kvoT_kernel<<<dim3(16, 4, B_), 256, 0, stream>>>(kvo, kvoT);
    // qe = [q_abs * SCALE | rope(q_pe) * SCALE]
    gemm64_mfma<bf16><<<dim3(256 / 64, M / 64, H_), 256, 0, stream>>>(
        q_bf, H_ * QKD_, QKD_, wkvbT, 64, 256 * 64, qe, H_ * 288, 288, 64, SCALE_);
    rope_qe_kernel<<<(M * H_ * 16 + 255) / 256, 256, 0, stream>>>(q_bf, qe);
    // self scores
    sscore_kernel<<<dim3(S_, B_), 256, 0, stream>>>(qe, kve_full, sscore);
    // attention
    attn2_kernel<<<dim3(S_ / 4, B_), 256, 0, stream>>>(qe, kvo, kvoT, kve_full, sscore, x_bf);
    // V-projection per head
    gemm64_mfma<bf16><<<dim3(1, M / 64, H_), 256, 0, stream>>>(
        x_bf, H_ * 256, 256, wkvb_bf + (size_t)64 * 256, 256, 128 * 256, outp_bf, 1024, 64, 256, 1.0f);
    // final out = outp @ wo^T
    gemm_bt_mfma<float><<<dim3(E_ / 128, M / 128), 256, 0, stream>>>(outp_bf, wo_bf, out, M, E_, 1024);
}

// Round 6
// 432.642 us; speedup vs baseline: 9.0948x; 1.1043x over previous
//
#include <hip/hip_runtime.h>
#include <hip/hip_bf16.h>
#include <math.h>
#include <stdint.h>

#define B_ 2
#define S_ 2048
#define E_ 2048
#define H_ 16
#define NOPE_ 64
#define ROPE_ 32
#define V_ 64
#define KVR_ 256
#define QKD_ 96
#define SCALE_ 0.10206207261596577f  /* 96^-0.5 */

typedef __hip_bfloat16 bf16;
typedef __attribute__((ext_vector_type(8))) short short8;
typedef __attribute__((ext_vector_type(4))) short short4v;
typedef __attribute__((ext_vector_type(4))) float floatx4;

__device__ __forceinline__ float bf2f(bf16 v) { return __bfloat162float(v); }
__device__ __forceinline__ float s2f(short v) {
    bf16 h = *reinterpret_cast<bf16*>(&v);
    return __bfloat162float(h);
}
__device__ __forceinline__ short f2bf_s(float f) {
    bf16 h = __float2bfloat16(f);
    return *reinterpret_cast<short*>(&h);
}
__device__ __forceinline__ void store_c(float* C, size_t i, float v) { C[i] = v; }
__device__ __forceinline__ void store_c(bf16* C, size_t i, float v) { C[i] = __float2bfloat16(v); }

// async 16B global -> LDS. Proper addrspacecasts (NO integer truncation — flat LDS
// addresses are aperture-based; C-style cast emits the correct addrspacecast).
__device__ __forceinline__ void g2l16(const bf16* g, bf16* l) {
    __builtin_amdgcn_global_load_lds(
        (const __attribute__((address_space(1))) void*)g,
        (__attribute__((address_space(3))) void*)l,
        16, 0, 0);
}

#if __has_builtin(__builtin_amdgcn_mfma_f32_16x16x16_bf16)
#define HAVE_M16 1
#define MFMA16(a, b, c) __builtin_amdgcn_mfma_f32_16x16x16_bf16(a, b, c, 0, 0, 0)
#elif __has_builtin(__builtin_amdgcn_mfma_f32_16x16x16bf16_1k)
#define HAVE_M16 1
#define MFMA16(a, b, c) __builtin_amdgcn_mfma_f32_16x16x16bf16_1k(a, b, c, 0, 0, 0)
#else
#define HAVE_M16 0
#endif

// ---------------- fp32 -> bf16 conversion ----------------
__global__ __launch_bounds__(256) void conv_bf16_kernel(const float* __restrict__ src,
                                                        bf16* __restrict__ dst, int n8) {
    int i = blockIdx.x * 256 + threadIdx.x;
    if (i >= n8) return;
    float4 a = ((const float4*)src)[2 * i];
    float4 b = ((const float4*)src)[2 * i + 1];
    short8 r;
    r[0] = f2bf_s(a.x); r[1] = f2bf_s(a.y); r[2] = f2bf_s(a.z); r[3] = f2bf_s(a.w);
    r[4] = f2bf_s(b.x); r[5] = f2bf_s(b.y); r[6] = f2bf_s(b.z); r[7] = f2bf_s(b.w);
    ((short8*)dst)[i] = r;
}

// ---------------- wkv_a (288x2048) -> zero-padded bf16 (384x2048) ----------------
__global__ __launch_bounds__(256) void conv_pad_wkva_kernel(const float* __restrict__ src,
                                                            bf16* __restrict__ dst) {
    int i = blockIdx.x * 256 + threadIdx.x;
    if (i >= 384 * 2048 / 8) return;
    int row = i >> 8;
    short8 r;
    if (row < 288) {
        float4 a = ((const float4*)src)[2 * i];
        float4 b = ((const float4*)src)[2 * i + 1];
        r[0] = f2bf_s(a.x); r[1] = f2bf_s(a.y); r[2] = f2bf_s(a.z); r[3] = f2bf_s(a.w);
        r[4] = f2bf_s(b.x); r[5] = f2bf_s(b.y); r[6] = f2bf_s(b.z); r[7] = f2bf_s(b.w);
    } else {
        for (int j = 0; j < 8; ++j) r[j] = 0;
    }
    ((short8*)dst)[i] = r;
}

// ---------------- wkvbT[h][c][d] = bf16(wkv_b[h*128+d][c]), d<64 ----------------
__global__ __launch_bounds__(256) void transpose_wkvbT_kernel(const float* __restrict__ wkv_b,
                                                              bf16* __restrict__ wkvbT) {
    int h = blockIdx.x, c = threadIdx.x;
#pragma unroll
    for (int d0 = 0; d0 < 64; d0 += 8) {
        short8 v;
#pragma unroll
        for (int j = 0; j < 8; ++j) v[j] = f2bf_s(wkv_b[(size_t)(h * 128 + d0 + j) * 256 + c]);
        *(short8*)(void*)&wkvbT[((size_t)h * 256 + c) * 64 + d0] = v;
    }
}

// ---------------- bf16 MFMA GEMM (m97-style): C(M,N) = A(M,K) @ B(N,K)^T ----------------
template <typename TC>
__global__ __launch_bounds__(256, 2) void gemm_bt_lds(const bf16* __restrict__ A,
                                                      const bf16* __restrict__ Bm,
                                                      TC* __restrict__ C,
                                                      int M, int N, int K) {
    __shared__ bf16 Asf[128 * 32];
    __shared__ bf16 Bsf[128 * 32];
    int tid = threadIdx.x;
    int lane = tid & 63, w = tid >> 6;
    int q4 = lane >> 4, c16 = lane & 15;
    int wr = w >> 1, wc = w & 1;
    int m0 = blockIdx.y * 128, n0 = blockIdx.x * 128;
    floatx4 acc[4][4];
#pragma unroll
    for (int mi = 0; mi < 4; ++mi)
#pragma unroll
        for (int ni = 0; ni < 4; ++ni) acc[mi][ni] = (floatx4){0.f, 0.f, 0.f, 0.f};

    for (int k0 = 0; k0 < K; k0 += 32) {
        __syncthreads();
#pragma unroll
        for (int i = 0; i < 2; ++i) {
            int c = (w << 6) + lane + i * 256;
            int row = c >> 2, kc = c & 3;
            g2l16(&A[(size_t)(m0 + row) * K + k0 + kc * 8], &Asf[c * 8]);
            g2l16(&Bm[(size_t)(n0 + row) * K + k0 + kc * 8], &Bsf[c * 8]);
        }
        __syncthreads();
        short8 af[4], bfr[4];
#pragma unroll
        for (int mi = 0; mi < 4; ++mi)
            af[mi] = *(const short8*)(const void*)&Asf[(wr * 64 + mi * 16 + c16) * 32 + q4 * 8];
#pragma unroll
        for (int ni = 0; ni < 4; ++ni)
            bfr[ni] = *(const short8*)(const void*)&Bsf[(wc * 64 + ni * 16 + c16) * 32 + q4 * 8];
#pragma unroll
        for (int mi = 0; mi < 4; ++mi)
#pragma unroll
            for (int ni = 0; ni < 4; ++ni)
                acc[mi][ni] = __builtin_amdgcn_mfma_f32_16x16x32_bf16(af[mi], bfr[ni], acc[mi][ni], 0, 0, 0);
    }
#pragma unroll
    for (int mi = 0; mi < 4; ++mi)
#pragma unroll
        for (int ni = 0; ni < 4; ++ni)
#pragma unroll
            for (int r = 0; r < 4; ++r) {
                int row = m0 + wr * 64 + mi * 16 + q4 * 4 + r;
                int col = n0 + wc * 64 + ni * 16 + c16;
                store_c(C, (size_t)row * N + col, acc[mi][ni][r]);
            }
}

// ---------------- small batched bf16 MFMA GEMM (64x64 tiles, global_load_lds) -------------
template <typename TC>
__global__ __launch_bounds__(256, 4) void gemm64_lds(const bf16* __restrict__ A, int lda, int aoffz,
                                                     const bf16* __restrict__ Bm, int ldb, int boffz,
                                                     TC* __restrict__ C, int ldc, int coffz,
                                                     int K, float scale) {
    int z = blockIdx.z;
    A += (size_t)z * aoffz;
    Bm += (size_t)z * boffz;
    C += (size_t)z * coffz;
    __shared__ bf16 Asf[64 * 32];
    __shared__ bf16 Bsf[64 * 32];
    int tid = threadIdx.x;
    int lane = tid & 63, w = tid >> 6;
    int q4 = lane >> 4, c16 = lane & 15;
    int m0 = blockIdx.y * 64, n0 = blockIdx.x * 64;
    floatx4 acc[4];
#pragma unroll
    for (int ni = 0; ni < 4; ++ni) acc[ni] = (floatx4){0.f, 0.f, 0.f, 0.f};
    int row = tid >> 2, kc = tid & 3;
    for (int k0 = 0; k0 < K; k0 += 32) {
        __syncthreads();
        g2l16(&A[(size_t)(m0 + row) * lda + k0 + kc * 8], &Asf[tid * 8]);
        g2l16(&Bm[(size_t)(n0 + row) * ldb + k0 + kc * 8], &Bsf[tid * 8]);
        __syncthreads();
        short8 af = *(const short8*)(const void*)&Asf[(w * 16 + c16) * 32 + q4 * 8];
#pragma unroll
        for (int ni = 0; ni < 4; ++ni) {
            short8 bfr = *(const short8*)(const void*)&Bsf[(ni * 16 + c16) * 32 + q4 * 8];
            acc[ni] = __builtin_amdgcn_mfma_f32_16x16x32_bf16(af, bfr, acc[ni], 0, 0, 0);
        }
    }
#pragma unroll
    for (int ni = 0; ni < 4; ++ni)
#pragma unroll
        for (int rr = 0; rr < 4; ++rr)
            store_c(C, (size_t)(m0 + w * 16 + q4 * 4 + rr) * ldc + n0 + ni * 16 + c16,
                    acc[ni][rr] * scale);
}

// ---------------- LayerNorm(kv_c) + RoPE(k_pe); input stride 384 ----------------
__global__ __launch_bounds__(256) void ln_rope_kernel(const float* __restrict__ kvraw,
                                                      const float* __restrict__ g,
                                                      const float* __restrict__ bta,
                                                      float* __restrict__ kv_c,
                                                      float* __restrict__ kpe) {
    int r = blockIdx.x;
    int tid = threadIdx.x;
    int lane = tid & 63, w = tid >> 6;
    float x = kvraw[(size_t)r * 384 + tid];
    float v1 = x, v2 = x * x;
#pragma unroll
    for (int o = 32; o; o >>= 1) { v1 += __shfl_down(v1, o); v2 += __shfl_down(v2, o); }
    __shared__ float s1[4], s2[4], stats[2];
    if (lane == 0) { s1[w] = v1; s2[w] = v2; }
    __syncthreads();
    if (tid == 0) {
        float S1 = s1[0] + s1[1] + s1[2] + s1[3];
        float S2 = s2[0] + s2[1] + s2[2] + s2[3];
        float mean = S1 / 256.0f;
        float var = S2 / 256.0f - mean * mean;
        stats[0] = mean;
        stats[1] = rsqrtf(var + 1e-5f);
    }
    __syncthreads();
    float y = (x - stats[0]) * stats[1] * g[tid] + bta[tid];
    kv_c[(size_t)r * 256 + tid] = y;
    if (tid < 16) {
        int j = tid;
        int s = r & (S_ - 1);
        float freq = expf(-(float)(2 * j) * 0.28782313662425572f);  // ln(1e4)/32
        float ang = (float)s * freq;
        float c = cosf(ang), sn = sinf(ang);
        float x0 = kvraw[(size_t)r * 384 + 256 + 2 * j];
        float x1 = kvraw[(size_t)r * 384 + 256 + 2 * j + 1];
        kpe[(size_t)r * 32 + 2 * j]     = x0 * c - x1 * sn;
        kpe[(size_t)r * 32 + 2 * j + 1] = x0 * sn + x1 * c;
    }
}

// ---------------- C2 / P2 ----------------
__global__ __launch_bounds__(64) void c2p2_kernel(const float* __restrict__ fcw_c,
                                                  const float* __restrict__ fcb_c,
                                                  const float* __restrict__ fcw_p,
                                                  const float* __restrict__ fcb_p,
                                                  float* __restrict__ C2,
                                                  float* __restrict__ P2) {
    int t = blockIdx.x;
    int k = threadIdx.x;
    __shared__ float Crow[256], Prow[256];
    for (int i = k; i < 128; i += 64) {
        float div = expf(-(float)i * 0.07195578415606393f);  // ln(1e4)/128
        float ap = (float)t * div;
        Prow[2 * i]     = sinf(ap);
        Prow[2 * i + 1] = cosf(ap);
        float ac = (float)(t >> 1) * div;
        Crow[2 * i]     = sinf(ac);
        Crow[2 * i + 1] = cosf(ac);
    }
    __syncthreads();
    float sc = fcb_c[k], sp = fcb_p[k];
    for (int c = 0; c < 256; ++c) {
        sc += Crow[c] * fcw_c[(size_t)k * 256 + c];
        sp += Prow[c] * fcw_p[(size_t)k * 256 + c];
    }
    C2[(size_t)t * 64 + k] = sc;
    P2[(size_t)t * 64 + k] = sp;
}

__global__ __launch_bounds__(256) void gates_kernel(const float* __restrict__ C2,
                                                    const float* __restrict__ P2,
                                                    float* __restrict__ g0,
                                                    float* __restrict__ g1) {
    int t = blockIdx.x * 256 + threadIdx.x;
    if (t >= S_) return;
    float d0 = 0.f;
    for (int k = 0; k < 64; ++k) d0 += C2[(size_t)t * 64 + k] * P2[(size_t)t * 64 + k];
    g0[t] = 1.0f / (1.0f + expf(-d0));
    float gg = 0.f;
    if (t & 1) {
        float d1 = 0.f;
        for (int k = 0; k < 64; ++k) d1 += C2[(size_t)t * 64 + k] * P2[(size_t)(t - 1) * 64 + k];
        gg = 1.0f / (1.0f + expf(-d1));
    }
    g1[t] = gg;
}

// ---------------- gated kv_t -> kve_full [B*S][288] + packed odd kvo [B][1024][296] ------
__global__ __launch_bounds__(256) void kve_kernel(const float* __restrict__ kv_c,
                                                  const float* __restrict__ kpe,
                                                  const float* __restrict__ g0,
                                                  const float* __restrict__ g1,
                                                  bf16* __restrict__ kve_full,
                                                  bf16* __restrict__ kvo) {
    int r = blockIdx.x, tid = threadIdx.x;
    int b = r >> 11, t = r & (S_ - 1);
    float a = g0[t], bb = g1[t];
    float v = a * kv_c[(size_t)r * 256 + tid];
    if (t & 1) v += bb * kv_c[(size_t)(r - 1) * 256 + tid];
    bf16 vb = __float2bfloat16(v);
    kve_full[(size_t)r * 288 + tid] = vb;
    if (t & 1) kvo[((size_t)b * 1024 + (t >> 1)) * 296 + tid] = vb;
    if (tid < 32) {
        float u = a * kpe[(size_t)r * 32 + tid];
        if (t & 1) u += bb * kpe[(size_t)(r - 1) * 32 + tid];
        bf16 ub = __float2bfloat16(u);
        kve_full[(size_t)r * 288 + 256 + tid] = ub;
        if (t & 1) kvo[((size_t)b * 1024 + (t >> 1)) * 296 + 256 + tid] = ub;
    }
}

// ---------------- kvoT[b][uch][c][16] = kvo[b][uch*16+j][c] ----------------
__global__ __launch_bounds__(256) void kvoT2_kernel(const bf16* __restrict__ kvo,
                                                    bf16* __restrict__ kvoT) {
    int uch = blockIdx.x, b = blockIdx.y;
    int c = threadIdx.x;
    const bf16* src = kvo + ((size_t)b * 1024 + uch * 16) * 296 + c;
    short8 o0, o1;
#pragma unroll
    for (int j = 0; j < 8; ++j) o0[j] = *(const short*)&src[(size_t)j * 296];
#pragma unroll
    for (int j = 0; j < 8; ++j) o1[j] = *(const short*)&src[(size_t)(8 + j) * 296];
    bf16* dst = kvoT + (((size_t)b * 64 + uch) * 256 + c) * 16;
    *(short8*)(void*)dst = o0;
    *(short8*)(void*)(dst + 8) = o1;
}

// ---------------- roped, scaled q_pe -> qe[...,256:288) ----------------
__global__ __launch_bounds__(256) void rope_qe_kernel(const bf16* __restrict__ q,
                                                      bf16* __restrict__ qe) {
    int idx = blockIdx.x * 256 + threadIdx.x;
    if (idx >= B_ * S_ * H_ * 16) return;
    int j = idx & 15;
    int s = (idx >> 8) & (S_ - 1);
    float freq = expf(-(float)(2 * j) * 0.28782313662425572f);
    float ang = (float)s * freq;
    float c = cosf(ang), sn = sinf(ang);
    size_t row = idx >> 4;
    float a0 = bf2f(q[row * QKD_ + NOPE_ + 2 * j]);
    float a1 = bf2f(q[row * QKD_ + NOPE_ + 2 * j + 1]);
    qe[row * 288 + 256 + 2 * j]     = __float2bfloat16((a0 * c - a1 * sn) * SCALE_);
    qe[row * 288 + 256 + 2 * j + 1] = __float2bfloat16((a0 * sn + a1 * c) * SCALE_);
}

// ---------------- self scores: sscore[b][s][h] ----------------
__global__ __launch_bounds__(256) void sscore_kernel(const bf16* __restrict__ qe,
                                                     const bf16* __restrict__ kve_full,
                                                     float* __restrict__ sscore) {
    int s = blockIdx.x, b = blockIdx.y;
    int tid = threadIdx.x;
    int h = tid >> 4, p = tid & 15;
    const bf16* qrow = qe + ((size_t)(b * S_ + s) * H_ + h) * 288;
    const bf16* krow = kve_full + (size_t)(b * S_ + s) * 288;
    float d = 0.f;
#pragma unroll
    for (int e = 0; e < 18; ++e) d += bf2f(qrow[p * 18 + e]) * bf2f(krow[p * 18 + e]);
    d += __shfl_xor(d, 1);
    d += __shfl_xor(d, 2);
    d += __shfl_xor(d, 4);
    d += __shfl_xor(d, 8);
    if (p == 0) sscore[((size_t)(b * S_ + s)) * H_ + h] = d;
}

// ---------------- transposed-score flash attention ----------------
// block = (b, 4 consecutive s); wave w owns s0+w. Scores D[u][h]; P stays in registers.
__global__ __launch_bounds__(256, 2) void attn3_kernel(const bf16* __restrict__ qe,
                                                       const bf16* __restrict__ kvo,
                                                       const bf16* __restrict__ kvoT,
                                                       const bf16* __restrict__ kve_full,
                                                       const float* __restrict__ sscore,
                                                       bf16* __restrict__ xout) {
    int s0 = (int)(gridDim.x - 1 - blockIdx.x) * 4;  // biggest blocks first
    int b = blockIdx.y;
    int tid = threadIdx.x;
    int lane = tid & 63, w = tid >> 6;
    int q4 = lane >> 4, c16 = lane & 15;
    int s = s0 + w;
    int Nodd = (s + 1) >> 1;
    int NoddMax = (s0 + 4) >> 1;
    int niterB = (NoddMax + 15) >> 4;

    __shared__ bf16 kvos[2][16][296];    // score tiles (K-side); 592B rows, 16B-aligned
    __shared__ bf16 kvoTs[2][256][24];   // PV tiles; 48B rows -> all 16B stores aligned
    __shared__ bf16 selfr[4][256];       // self-key kv rows

    const bf16* kvob = kvo + (size_t)b * 1024 * 296;
    const bf16* kvoTb = kvoT + (size_t)b * 64 * 4096;

    if (tid < 128) {
        int rr = tid >> 5, ch = tid & 31;
        *(short8*)(void*)&selfr[rr][ch * 8] =
            *(const short8*)(const void*)&kve_full[(size_t)(b * S_ + s0 + rr) * 288 + ch * 8];
    }

    short8 qf[9];
    const bf16* qrow = qe + ((size_t)(b * S_ + s) * H_ + c16) * 288;
#pragma unroll
    for (int kk = 0; kk < 9; ++kk) qf[kk] = *(const short8*)(const void*)&qrow[kk * 32 + q4 * 8];

    floatx4 acc[16];
#pragma unroll
    for (int n = 0; n < 16; ++n) acc[n] = (floatx4){0.f, 0.f, 0.f, 0.f};
    float m_i = -1e30f, l_i = 0.f;

    short8 ra[3], rb[2];
    auto load_regs = [&](int t) {
        const short8* sa = (const short8*)(const void*)(kvob + (size_t)t * 16 * 296);
#pragma unroll
        for (int i = 0; i < 3; ++i) {
            int idx = tid + i * 256;
            if (idx < 592) ra[i] = sa[idx];
        }
        const short8* sb = (const short8*)(const void*)(kvoTb + (size_t)t * 4096);
#pragma unroll
        for (int i = 0; i < 2; ++i) rb[i] = sb[tid + i * 256];
    };
    auto write_lds = [&](int p) {
        short8* da = (short8*)(void*)&kvos[p][0][0];
#pragma unroll
        for (int i = 0; i < 3; ++i) {
            int idx = tid + i * 256;
            if (idx < 592) da[idx] = ra[i];
        }
#pragma unroll
        for (int i = 0; i < 2; ++i) {
            int idx = tid + i * 256;
            *(short8*)(void*)&kvoTs[p][idx >> 1][(idx & 1) * 8] = rb[i];
        }
    };

    load_regs(0);
    write_lds(0);
    if (niterB > 1) load_regs(1);
    __syncthreads();

    for (int it = 0; it < niterB; ++it) {
        int p = it & 1;
        if (it + 1 < niterB) {
            write_lds(1 - p);
            if (it + 2 < niterB) load_regs(it + 2);
        }
        int u0 = it * 16;
        // scores^T: D[u][h], A = kvos rows (m=u), B = qf (n=h)
        floatx4 cf = (floatx4){0.f, 0.f, 0.f, 0.f};
#pragma unroll
        for (int kk = 0; kk < 9; ++kk) {
            short8 av = *(const short8*)(const void*)&kvos[p][c16][kk * 32 + q4 * 8];
            cf = __builtin_amdgcn_mfma_f32_16x16x32_bf16(av, qf[kk], cf, 0, 0, 0);
        }
        int ub = u0 + q4 * 4;
#pragma unroll
        for (int r = 0; r < 4; ++r)
            if (ub + r >= Nodd) cf[r] = -1e30f;
        float tmax = fmaxf(fmaxf(cf[0], cf[1]), fmaxf(cf[2], cf[3]));
        tmax = fmaxf(tmax, __shfl_xor(tmax, 16));
        tmax = fmaxf(tmax, __shfl_xor(tmax, 32));
        float mn = fmaxf(m_i, tmax);
        bool chg = mn > m_i;
        float al = __expf(m_i - mn);
        float p0 = __expf(cf[0] - mn), p1 = __expf(cf[1] - mn);
        float p2 = __expf(cf[2] - mn), p3 = __expf(cf[3] - mn);
        float rs = p0 + p1 + p2 + p3;
        rs += __shfl_xor(rs, 16);
        rs += __shfl_xor(rs, 32);
        l_i = l_i * al + rs;
        m_i = mn;
        if (__any(chg)) {
#pragma unroll
            for (int n = 0; n < 16; ++n) {
                acc[n][0] *= al; acc[n][1] *= al; acc[n][2] *= al; acc[n][3] *= al;
            }
        }
        // P (C-layout) == PV B-frag (k = q4*4+j) — zero register shuffling needed
#if HAVE_M16
        short4v pfv;
        pfv[0] = f2bf_s(p0); pfv[1] = f2bf_s(p1); pfv[2] = f2bf_s(p2); pfv[3] = f2bf_s(p3);
#pragma unroll
        for (int n = 0; n < 16; ++n) {
            short4v a4 = *(const short4v*)(const void*)&kvoTs[p][n * 16 + c16][q4 * 4];
            acc[n] = MFMA16(a4, pfv, acc[n]);
        }
#else
        short8 pf;
        pf[0] = f2bf_s(p0); pf[1] = f2bf_s(p1); pf[2] = f2bf_s(p2); pf[3] = f2bf_s(p3);
        pf[4] = 0; pf[5] = 0; pf[6] = 0; pf[7] = 0;
#pragma unroll
        for (int n = 0; n < 16; ++n) {
            short4v a4 = *(const short4v*)(const void*)&kvoTs[p][n * 16 + c16][q4 * 4];
            short8 af;
            af[0] = a4[0]; af[1] = a4[1]; af[2] = a4[2]; af[3] = a4[3];
            af[4] = 0; af[5] = 0; af[6] = 0; af[7] = 0;
            acc[n] = __builtin_amdgcn_mfma_f32_16x16x32_bf16(af, pf, acc[n], 0, 0, 0);
        }
#endif
        __syncthreads();
    }

    // self key (even s; odd s already included in odd set)
    if ((s & 1) == 0) {
        float scs = sscore[((size_t)(b * S_ + s)) * H_ + c16];
        float mn = fmaxf(m_i, scs);
        float al = __expf(m_i - mn);
        float pp = __expf(scs - mn);
        l_i = l_i * al + pp;
        m_i = mn;
#pragma unroll
        for (int n = 0; n < 16; ++n) {
            short4v kv4 = *(const short4v*)(const void*)&selfr[w][n * 16 + q4 * 4];
#pragma unroll
            for (int r = 0; r < 4; ++r)
                acc[n][r] = acc[n][r] * al + pp * s2f(kv4[r]);
        }
    }

    float invl = 1.0f / l_i;
    bf16* orow = xout + ((size_t)(b * S_ + s) * H_ + c16) * 256;
#pragma unroll
    for (int n = 0; n < 16; ++n) {
        short4v o;
        o[0] = f2bf_s(acc[n][0] * invl);
        o[1] = f2bf_s(acc[n][1] * invl);
        o[2] = f2bf_s(acc[n][2] * invl);
        o[3] = f2bf_s(acc[n][3] * invl);
        *(short4v*)(void*)&orow[n * 16 + q4 * 4] = o;
    }
}

extern "C" void kernel_launch(void* const* d_in, const int* in_sizes, int n_in,
                              void* d_out, int out_size, void* d_ws, size_t ws_size,
                              hipStream_t stream) {
    const float* hs     = (const float*)d_in[0];
    const float* wq     = (const float*)d_in[1];
    const float* wkv_a  = (const float*)d_in[2];
    const float* ln_g   = (const float*)d_in[3];
    const float* ln_b   = (const float*)d_in[4];
    const float* wkv_b  = (const float*)d_in[5];
    const float* wo     = (const float*)d_in[6];
    const float* fc_c_w = (const float*)d_in[7];
    const float* fc_c_b = (const float*)d_in[8];
    const float* fc_p_w = (const float*)d_in[9];
    const float* fc_p_b = (const float*)d_in[10];
    float* out = (float*)d_out;
    (void)in_sizes; (void)n_in; (void)out_size; (void)ws_size;

    const int M = B_ * S_;  // 4096
    char* wsb = (char*)d_ws;
    size_t o = 0;
    auto alloc = [&](size_t bytes) { char* p = wsb + o; o += (bytes + 255) & ~(size_t)255; return p; };

    bf16* qe = (bf16*)alloc((size_t)M * H_ * 288 * 2);  // 37.75 MB
    char* region2 = alloc((size_t)M * H_ * 256 * 2);    // 33.55 MB
    bf16* hs_bf    = (bf16*)region2;
    bf16* wq_bf    = (bf16*)(region2 + (size_t)M * E_ * 2);
    bf16* wkva_pad = (bf16*)(region2 + (size_t)M * E_ * 2 + (size_t)1536 * E_ * 2);
    bf16* x_bf     = (bf16*)region2;
    char* region3 = alloc((size_t)M * 1536 * 2);        // 12.58 MB
    bf16* q_bf    = (bf16*)region3;
    bf16* outp_bf = (bf16*)region3;
    float* kvraw = (float*)alloc((size_t)M * 384 * 4);
    float* kv_c  = (float*)alloc((size_t)M * 256 * 4);
    float* kpe   = (float*)alloc((size_t)M * 32 * 4);
    bf16* wo_bf   = (bf16*)alloc((size_t)E_ * 1024 * 2);
    bf16* wkvb_bf = (bf16*)alloc((size_t)2048 * 256 * 2);
    bf16* wkvbT   = (bf16*)alloc((size_t)H_ * 256 * 64 * 2);
    bf16* kve_full = (bf16*)alloc((size_t)M * 288 * 2);
    bf16* kvo      = (bf16*)alloc((size_t)B_ * 1024 * 296 * 2);
    bf16* kvoT     = (bf16*)alloc((size_t)B_ * 64 * 4096 * 2);
    float* sscore  = (float*)alloc((size_t)M * H_ * 4);
    float* C2 = (float*)alloc((size_t)S_ * 64 * 4);
    float* P2 = (float*)alloc((size_t)S_ * 64 * 4);
    float* g0 = (float*)alloc(S_ * 4);
    float* g1 = (float*)alloc(S_ * 4);

    // conversions
    conv_bf16_kernel<<<(M * E_ / 8 + 255) / 256, 256, 0, stream>>>(hs, hs_bf, M * E_ / 8);
    conv_bf16_kernel<<<(1536 * E_ / 8 + 255) / 256, 256, 0, stream>>>(wq, wq_bf, 1536 * E_ / 8);
    conv_bf16_kernel<<<(E_ * 1024 / 8 + 255) / 256, 256, 0, stream>>>(wo, wo_bf, E_ * 1024 / 8);
    conv_bf16_kernel<<<(2048 * 256 / 8 + 255) / 256, 256, 0, stream>>>(wkv_b, wkvb_bf, 2048 * 256 / 8);
    conv_pad_wkva_kernel<<<(384 * 2048 / 8 + 255) / 256, 256, 0, stream>>>(wkv_a, wkva_pad);
    transpose_wkvbT_kernel<<<H_, 256, 0, stream>>>(wkv_b, wkvbT);
    // projections (m97-style MFMA GEMM)
    gemm_bt_lds<bf16><<<dim3(1536 / 128, M / 128), 256, 0, stream>>>(hs_bf, wq_bf, q_bf, M, 1536, E_);
    gemm_bt_lds<float><<<dim3(384 / 128, M / 128), 256, 0, stream>>>(hs_bf, wkva_pad, kvraw, M, 384, E_);
    // LN + k_pe rope
    ln_rope_kernel<<<M, 256, 0, stream>>>(kvraw, ln_g, ln_b, kv_c, kpe);
    // gates
    c2p2_kernel<<<S_, 64, 0, stream>>>(fc_c_w, fc_c_b, fc_p_w, fc_p_b, C2, P2);
    gates_kernel<<<(S_ + 255) / 256, 256, 0, stream>>>(C2, P2, g0, g1);
    // kve (full + packed odd) and u-chunked transpose
    kve_kernel<<<M, 256, 0, stream>>>(kv_c, kpe, g0, g1, kve_full, kvo);
    kvoT2_kernel<<<dim3(64, B_), 256, 0, stream>>>(kvo, kvoT);
    // qe = [q_abs * SCALE | rope(q_pe) * SCALE]
    gemm64_lds<bf16><<<dim3(256 / 64, M / 64, H_), 256, 0, stream>>>(
        q_bf, H_ * QKD_, QKD_, wkvbT, 64, 256 * 64, qe, H_ * 288, 288, 64, SCALE_);
    rope_qe_kernel<<<(M * H_ * 16 + 255) / 256, 256, 0, stream>>>(q_bf, qe);
    // self scores
    sscore_kernel<<<dim3(S_, B_), 256, 0, stream>>>(qe, kve_full, sscore);
    // attention
    attn3_kernel<<<dim3(S_ / 4, B_), 256, 0, stream>>>(qe, kvo, kvoT, kve_full, sscore, x_bf);
    // V-projection per head
    gemm64_lds<bf16><<<dim3(1, M / 64, H_), 256, 0, stream>>>(
        x_bf, H_ * 256, 256, wkvb_bf + (size_t)64 * 256, 256, 128 * 256, outp_bf, 1024, 64, 256, 1.0f);
    // final out = outp @ wo^T
    gemm_bt_lds<float><<<dim3(E_ / 128, M / 128), 256, 0, stream>>>(outp_bf, wo_bf, out, M, E_, 1024);
}